// Round 8
// baseline (172.074 us; speedup 1.0000x reference)
//
#include <hip/hip_runtime.h>
#include <hip/hip_bf16.h>
#include <hip/hip_fp16.h>

#define BB 16
#define NN 1024
#define CS 256
#define CX 64
#define CC 320
#define PH 64
#define GH 128
#define ELLW 64
#define NENG 7812   // 8-neigh edges per image (H=W=32)
#define NKPH 1128   // kp half-pairs (a<y)
#define NGU  3906   // undirected ng edges (forward dirs 0..3)
#define NUD  5034   // total undirected edges per image (NKPH + NGU)

typedef __hip_bfloat16 bf16;
typedef __attribute__((ext_vector_type(8))) __bf16 bfrag;   // 8 bf16 = 4 VGPRs
typedef __attribute__((ext_vector_type(4))) float v4f;

// triangular decode: m in [0,1128) -> pair (a,y), a<y, kp slots 0..47
__device__ __forceinline__ void tri_decode(int m, int& a, int& y) {
    float s = sqrtf((float)(9025 - 8 * m));
    int aa = (int)((95.0f - s) * 0.5f);
    if (aa > 0 && 47 * aa - (aa * (aa - 1)) / 2 > m) --aa;
    while (47 * (aa + 1) - ((aa + 1) * aa) / 2 <= m) ++aa;
    a = aa;
    y = aa + 1 + (m - (47 * aa - (aa * (aa - 1)) / 2));
}

// ---- merged prep (W packing, zero-init) + transpose [B,C,N]->[B,N,C] ----
__global__ __launch_bounds__(256) void k_prep_transpose(
    const float* __restrict__ search, const float* __restrict__ xcorr,
    float* __restrict__ featT,
    const float* __restrict__ w1, const float* __restrict__ gc1w,
    __bf16* __restrict__ whi, __bf16* __restrict__ wlo,
    __bf16* __restrict__ gwhi, __bf16* __restrict__ gwlo,
    int* __restrict__ cnt, float* __restrict__ Ssum, float* __restrict__ S2sum)
{
    __shared__ float tile[32][33];
    int blk = blockIdx.x;
    int tid = threadIdx.x;
    if (blk < BB * 320) {
        int b   = blk % BB;
        int rem = blk / BB;       // 0..319
        int ct  = rem >> 5;       // 10 channel tiles
        int ntl = rem & 31;       // 32 node tiles
        int cl = tid >> 5, nl = tid & 31;
        const float* sb = search + (size_t)b * CS * NN;
        const float* xb = xcorr + (size_t)b * CX * NN;
        #pragma unroll
        for (int f = 0; f < 4; ++f) {
            int c = ct * 32 + cl + f * 8;
            int n = ntl * 32 + nl;
            float v = (c < CS) ? sb[(size_t)c * NN + n] : xb[(size_t)(c - CS) * NN + n];
            tile[cl + f * 8][nl] = v;
        }
        __syncthreads();
        #pragma unroll
        for (int f = 0; f < 4; ++f) {
            int nr = cl + f * 8;
            int cc = nl;
            featT[((size_t)b * NN + ntl * 32 + nr) * CC + ct * 32 + cc] = tile[cc][nr];
        }
    } else {
        int idx = (blk - BB * 320) * 256 + tid;
        if (idx < 10 * 4 * 64 * 8) {          // W1: PH=64 -> 4 ntiles
            int j    = idx & 7;
            int lane = (idx >> 3) & 63;
            int nt   = (idx >> 9) & 3;
            int ks   = idx >> 11;
            int k = ks * 32 + (lane >> 4) * 8 + j;
            int n = nt * 16 + (lane & 15);
            float w = w1[k * PH + n];
            __bf16 h = (__bf16)w;
            whi[idx] = h;
            wlo[idx] = (__bf16)(w - (float)h);
        }
        if (idx < 10 * 8 * 64 * 8) {          // gc1_w: GH=128 -> 8 ntiles
            int j    = idx & 7;
            int lane = (idx >> 3) & 63;
            int nt   = (idx >> 9) & 7;
            int ks   = idx >> 12;
            int k = ks * 32 + (lane >> 4) * 8 + j;
            int n = nt * 16 + (lane & 15);
            float w = gc1w[k * GH + n];
            __bf16 h = (__bf16)w;
            gwhi[idx] = h;
            gwlo[idx] = (__bf16)(w - (float)h);
        }
        if (idx < BB * NN) cnt[idx] = 0;
        if (idx < BB * PH) { Ssum[idx] = 0.f; S2sum[idx] = 0.f; }
    }
}

// ------ stage 1: FINE-GRAINED, NO-LDS edge kernel.
//   1312 blocks x 256 thr, 4 waves/SIMD (512B LDS, VGPR-capped 128).
//   Blocks [0,1024): ng — wave = one (b, y, d, mt): 16 edges x full K.
//   Blocks [1024,1312): kp — b-uniform, wave = unit u = (kblk%18)*4+wave.
//   A-fragments read DIRECTLY from featT (L2-resident); W from global.
__global__ __launch_bounds__(256, 4) void k_edge(
    const float* __restrict__ featT, const int* __restrict__ pairs,
    const __bf16* __restrict__ wglob, const float* __restrict__ b1,
    bf16* __restrict__ hstore, float* __restrict__ Ssum,
    float* __restrict__ S2sum, int E, int EKP)
{
    __shared__ float sS[PH];
    __shared__ float sS2[PH];

    int t = threadIdx.x;
    int wave = t >> 6, lane = t & 63;
    int q = lane >> 4, r = lane & 15;

    const bfrag* WH = (const bfrag*)wglob;          // 2560 fragments (40 KB)
    const bfrag* WL = WH + 2560;                    // lo half

    float b1v[4];
    #pragma unroll
    for (int nt = 0; nt < 4; ++nt) b1v[nt] = b1[nt * 16 + r];
    float ps[4], ps2[4];
    #pragma unroll
    for (int nt = 0; nt < 4; ++nt) { ps[nt] = 0.f; ps2[nt] = 0.f; }
    int b;

    if (blockIdx.x < 1024) {
        // ---------------- ng branch: wave-unit (b, y, d, mt) --------------
        int blk = blockIdx.x;
        b = blk >> 6;
        int rb = blk & 63;
        int mt = rb >> 5;                 // 0..1
        int d  = (rb >> 3) & 3;           // 0..3
        int y  = ((rb & 7) << 2) + wave;  // 0..31 (4 consecutive y per block)

        const int dyT[4] = {-1,-1,-1, 0};
        const int dxT[4] = {-1, 0, 1,-1};
        const int pfT4[4] = {0, 961, 1953, 2914};
        int dy = dyT[d], dx = dxT[d];
        int y0 = dy < 0 ? 1 : 0;
        int x0 = dx < 0 ? 1 : 0;
        int ww = (dx == 0) ? 32 : 31;
        int pfF = pfT4[d];

        int xiL = mt * 16 + r;
        int ni = y * 32 + xiL;
        int xj = xiL + dx; xj = xj < 0 ? 0 : (xj > 31 ? 31 : xj);
        int gy = y + dy; int gyc = gy < 0 ? 0 : gy;
        int nj = gyc * 32 + xj;
        const float* rI = featT + ((size_t)b * NN + ni) * CC + q * 8;
        const float* rJ = featT + ((size_t)b * NN + nj) * CC + q * 8;

        v4f acc[4];
        #pragma unroll
        for (int nt = 0; nt < 4; ++nt) acc[nt] = (v4f)0.f;

        #pragma unroll
        for (int ks = 0; ks < 10; ++ks) {
            float4 fi0 = *(const float4*)(rI + ks * 32);
            float4 fi1 = *(const float4*)(rI + ks * 32 + 4);
            float4 fj0 = *(const float4*)(rJ + ks * 32);
            float4 fj1 = *(const float4*)(rJ + ks * 32 + 4);
            float df[8];
            df[0] = fabsf(fi0.x - fj0.x); df[1] = fabsf(fi0.y - fj0.y);
            df[2] = fabsf(fi0.z - fj0.z); df[3] = fabsf(fi0.w - fj0.w);
            df[4] = fabsf(fi1.x - fj1.x); df[5] = fabsf(fi1.y - fj1.y);
            df[6] = fabsf(fi1.z - fj1.z); df[7] = fabsf(fi1.w - fj1.w);

            bfrag ah, al;
            #pragma unroll
            for (int kk = 0; kk < 8; ++kk) {
                __bf16 h = (__bf16)df[kk];
                ah[kk] = h;
                al[kk] = (__bf16)(df[kk] - (float)h);
            }
            #pragma unroll
            for (int nt = 0; nt < 4; ++nt) {
                bfrag bh = WH[((ks * 4 + nt) << 6) + lane];
                bfrag bl = WL[((ks * 4 + nt) << 6) + lane];
                acc[nt] = __builtin_amdgcn_mfma_f32_16x16x32_bf16(ah, bh, acc[nt], 0, 0, 0);
                acc[nt] = __builtin_amdgcn_mfma_f32_16x16x32_bf16(ah, bl, acc[nt], 0, 0, 0);
                acc[nt] = __builtin_amdgcn_mfma_f32_16x16x32_bf16(al, bh, acc[nt], 0, 0, 0);
            }
        }

        // ng store (FORWARD only) + BN stats
        #pragma unroll
        for (int reg = 0; reg < 4; ++reg) {
            int xi = mt * 16 + q * 4 + reg;
            int y2 = y + dy, x2 = xi + dx;
            bool valid = ((unsigned)y2 < 32u) && ((unsigned)x2 < 32u);
            if (valid) {
                int e1 = EKP + pfF + (y - y0) * ww + (xi - x0);
                bf16* h1 = hstore + ((size_t)b * E + e1) * PH + r;
                #pragma unroll
                for (int nt = 0; nt < 4; ++nt) {
                    float v = acc[nt][reg] + b1v[nt];
                    h1[nt * 16] = __float2bfloat16(v);
                    ps[nt] += v;
                    ps2[nt] = fmaf(v, v, ps2[nt]);
                }
            }
        }
    } else {
        // ---------------- kp branch: b-uniform blocks ---------------------
        int kblk = blockIdx.x - 1024;     // 0..287
        b = kblk / 18;
        int u = (kblk % 18) * 4 + wave;   // 0..71; u==71 idle
        if (u < 71) {
            int mA = u * 16 + r;
            if (mA >= NKPH) mA = NKPH - 1;
            int aI, yI;
            tri_decode(mA, aI, yI);
            int na = pairs[((size_t)b * E + aI * 47) * 2];
            int ny = pairs[((size_t)b * E + yI * 47) * 2];
            const float* rI = featT + ((size_t)b * NN + na) * CC + q * 8;
            const float* rJ = featT + ((size_t)b * NN + ny) * CC + q * 8;

            v4f acc2[4];
            #pragma unroll
            for (int nt = 0; nt < 4; ++nt) acc2[nt] = (v4f)0.f;

            #pragma unroll
            for (int ks = 0; ks < 10; ++ks) {
                float4 fi0 = *(const float4*)(rI + ks * 32);
                float4 fi1 = *(const float4*)(rI + ks * 32 + 4);
                float4 fj0 = *(const float4*)(rJ + ks * 32);
                float4 fj1 = *(const float4*)(rJ + ks * 32 + 4);
                float df[8];
                df[0] = fabsf(fi0.x - fj0.x); df[1] = fabsf(fi0.y - fj0.y);
                df[2] = fabsf(fi0.z - fj0.z); df[3] = fabsf(fi0.w - fj0.w);
                df[4] = fabsf(fi1.x - fj1.x); df[5] = fabsf(fi1.y - fj1.y);
                df[6] = fabsf(fi1.z - fj1.z); df[7] = fabsf(fi1.w - fj1.w);

                bfrag ah, al;
                #pragma unroll
                for (int kk = 0; kk < 8; ++kk) {
                    __bf16 h = (__bf16)df[kk];
                    ah[kk] = h;
                    al[kk] = (__bf16)(df[kk] - (float)h);
                }
                #pragma unroll
                for (int nt = 0; nt < 4; ++nt) {
                    bfrag bh = WH[((ks * 4 + nt) << 6) + lane];
                    bfrag bl = WL[((ks * 4 + nt) << 6) + lane];
                    acc2[nt] = __builtin_amdgcn_mfma_f32_16x16x32_bf16(ah, bh, acc2[nt], 0, 0, 0);
                    acc2[nt] = __builtin_amdgcn_mfma_f32_16x16x32_bf16(ah, bl, acc2[nt], 0, 0, 0);
                    acc2[nt] = __builtin_amdgcn_mfma_f32_16x16x32_bf16(al, bh, acc2[nt], 0, 0, 0);
                }
            }

            #pragma unroll
            for (int reg = 0; reg < 4; ++reg) {
                int mC = u * 16 + q * 4 + reg;
                if (mC < NKPH) {
                    int a, yk;
                    tri_decode(mC, a, yk);
                    int e1 = a * 47 + yk - 1;    // forward (a,yk), a<yk
                    bf16* h1 = hstore + ((size_t)b * E + e1) * PH + r;
                    #pragma unroll
                    for (int nt = 0; nt < 4; ++nt) {
                        float v = acc2[nt][reg] + b1v[nt];
                        h1[nt * 16] = __float2bfloat16(v);
                        ps[nt] += v;
                        ps2[nt] = fmaf(v, v, ps2[nt]);
                    }
                }
            }
        }
    }

    // common BN reduce: cross-lane q-sum, LDS atomics, global atomics.
    // x2 for symmetric duplicate edges.
    if (t < PH) { sS[t] = 0.f; sS2[t] = 0.f; }
    __syncthreads();
    #pragma unroll
    for (int nt = 0; nt < 4; ++nt) {
        float p1 = ps[nt]  + __shfl_xor(ps[nt], 16, 64);
        p1 += __shfl_xor(p1, 32, 64);
        float p2 = ps2[nt] + __shfl_xor(ps2[nt], 16, 64);
        p2 += __shfl_xor(p2, 32, 64);
        if (lane < 16) {
            atomicAdd(&sS[nt * 16 + r],  2.0f * p1);
            atomicAdd(&sS2[nt * 16 + r], 2.0f * p2);
        }
    }
    __syncthreads();
    if (t < PH) {
        atomicAdd(&Ssum[b * PH + t],  sS[t]);
        atomicAdd(&S2sum[b * PH + t], sS2[t]);
    }
}

// -- merged: gc1 (blocks [0,512)) + BN-final/edge-val over UNDIRECTED edges
//    (blocks [512, 512+16*20)): one h read + sigmoid per undirected edge,
//    scatter BOTH ELL directions.  g1 stored as FP16 (halves spmm1 gather).
__global__ __launch_bounds__(256, 2) void k_val_gc1(
    const float* __restrict__ featT, const __bf16* __restrict__ gwhi,
    const __bf16* __restrict__ gwlo, __half* __restrict__ g1,
    const bf16* __restrict__ hstore, const float* __restrict__ Ssum,
    const float* __restrict__ S2sum, const float* __restrict__ gamma,
    const float* __restrict__ beta, const float* __restrict__ w2,
    const float* __restrict__ b2, const int* __restrict__ pairs,
    int* __restrict__ cnt, int* __restrict__ ecol, float* __restrict__ eval_,
    int E, int EKP, int nGC)
{
    __shared__ ushort WG[40960];   // 80 KB (gc1); edge_val reuses <1 KB of it

    int t = threadIdx.x;
    if ((int)blockIdx.x < nGC) {
        // -------------------- gc1 branch --------------------
        int b = blockIdx.x % BB;
        int rem = blockIdx.x / BB;     // 0..31
        int half = rem & 1;
        int m0 = b * NN + (rem >> 1) * 64;

        {
            uint4* dst = (uint4*)WG;
            const uint4* sh = (const uint4*)gwhi;
            const uint4* sl = (const uint4*)gwlo;
            #pragma unroll
            for (int k = 0; k < 10; ++k) {
                int u = t + k * 256;
                int chunk = u >> 6, v = u & 63;
                int ks = chunk >> 2, ntp = chunk & 3;
                int src = (ks * 8 + half * 4 + ntp) * 64 + v;
                dst[u]        = sh[src];
                dst[2560 + u] = sl[src];
            }
        }

        int wave = t >> 6, lane = t & 63;
        int q = lane >> 4, r = lane & 15;
        const float* fp = featT + (size_t)(m0 + wave * 16 + r) * CC + q * 8;

        float fa[2][8];
        auto LOADA = [&](int ks, int buf) {
            const float4* p = (const float4*)(fp + ks * 32);
            *(float4*)&fa[buf][0] = p[0];
            *(float4*)&fa[buf][4] = p[1];
        };

        v4f acc[4];
        #pragma unroll
        for (int nt = 0; nt < 4; ++nt) acc[nt] = (v4f)0.f;

        LOADA(0, 0);
        __syncthreads();

        const bfrag* WGH = (const bfrag*)WG;
        const bfrag* WGL = (const bfrag*)(WG + 20480);

        #pragma unroll
        for (int ks = 0; ks < 10; ++ks) {
            int cur = ks & 1;
            if (ks < 9) LOADA(ks + 1, cur ^ 1);
            bfrag ah, al;
            #pragma unroll
            for (int kk = 0; kk < 8; ++kk) {
                float d = fa[cur][kk];
                __bf16 h = (__bf16)d;
                ah[kk] = h;
                al[kk] = (__bf16)(d - (float)h);
            }
            #pragma unroll
            for (int nt = 0; nt < 4; ++nt) {
                bfrag bh = WGH[((ks * 4 + nt) << 6) + lane];
                bfrag bl = WGL[((ks * 4 + nt) << 6) + lane];
                acc[nt] = __builtin_amdgcn_mfma_f32_16x16x32_bf16(ah, bh, acc[nt], 0, 0, 0);
                acc[nt] = __builtin_amdgcn_mfma_f32_16x16x32_bf16(ah, bl, acc[nt], 0, 0, 0);
                acc[nt] = __builtin_amdgcn_mfma_f32_16x16x32_bf16(al, bh, acc[nt], 0, 0, 0);
            }
        }
        #pragma unroll
        for (int nt = 0; nt < 4; ++nt) {
            #pragma unroll
            for (int reg = 0; reg < 4; ++reg) {
                int m = m0 + wave * 16 + q * 4 + reg;
                g1[(size_t)m * GH + (half * 4 + nt) * 16 + r] =
                    __float2half(acc[nt][reg]);
            }
        }
    } else {
        // ---------- edge_val branch: undirected edges, dual scatter --------
        float* ca = (float*)WG;
        float* cb = ca + PH;
        int* kpl = (int*)(cb + PH);
        int blk = blockIdx.x - nGC;
        int b = blk % BB;
        int u = (blk / BB) * 256 + t;
        if (t < PH) {
            int l = t;
            float mu = Ssum[b * PH + l] / E;
            float var = S2sum[b * PH + l] / E - mu * mu;
            float A = rsqrtf(var + 1e-5f) * gamma[l];
            ca[l] = A;
            cb[l] = beta[l] - mu * A;
        }
        if (t < 48) kpl[t] = pairs[((size_t)b * E + t * 47) * 2];
        __syncthreads();
        if (u >= NUD) return;

        int i, j, hrow;
        if (u < NKPH) {
            int a, yk;
            tri_decode(u, a, yk);
            i = kpl[a]; j = kpl[yk];
            hrow = a * 47 + yk - 1;
        } else {
            int up = u - NKPH;           // [0, 3906) forward-region offset
            int pf, ww, y0, x0, dy, dx;
            if (up < 961)       { pf = 0;    ww = 31; y0 = 1; x0 = 1; dy = -1; dx = -1; }
            else if (up < 1953) { pf = 961;  ww = 32; y0 = 1; x0 = 0; dy = -1; dx = 0;  }
            else if (up < 2914) { pf = 1953; ww = 31; y0 = 1; x0 = 0; dy = -1; dx = 1;  }
            else                { pf = 2914; ww = 31; y0 = 0; x0 = 1; dy = 0;  dx = -1; }
            int rel = up - pf;
            int yR = rel / ww, xC = rel - yR * ww;
            int yy = yR + y0, xi = xC + x0;
            i = yy * 32 + xi;
            j = (yy + dy) * 32 + (xi + dx);
            hrow = EKP + up;             // undirected ng id == forward hstore offset
        }

        const bfrag* hp = (const bfrag*)(hstore + ((size_t)b * E + hrow) * PH);
        float acc = 0.f;
        #pragma unroll
        for (int l8 = 0; l8 < 8; ++l8) {
            bfrag hv = hp[l8];
            #pragma unroll
            for (int c = 0; c < 8; ++c) {
                int l = l8 * 8 + c;
                float x = fmaf((float)hv[c], ca[l], cb[l]);
                x = x > 0.f ? x : 0.f;
                acc = fmaf(x, w2[l], acc);
            }
        }
        float edge = 1.f / (1.f + __expf(-(acc + b2[0])));
        int ri = b * NN + i;
        int rj = b * NN + j;
        int s1 = atomicAdd(&cnt[ri], 1);
        if (s1 < ELLW) {
            ecol[ri * ELLW + s1]  = j;
            eval_[ri * ELLW + s1] = edge;
        }
        int s2 = atomicAdd(&cnt[rj], 1);
        if (s2 < ELLW) {
            ecol[rj * ELLW + s2]  = i;
            eval_[rj * ELLW + s2] = edge;
        }
    }
}

// ------- stage 5: g2 = (leaky(adj@g1)) @ gc2_w  (4 nodes/block, f16 g1) --
__global__ __launch_bounds__(256) void k_spmm1(
    const __half* __restrict__ g1, const int* __restrict__ cnt,
    const int* __restrict__ ecol, const float* __restrict__ eval_,
    const float* __restrict__ w2g, float* __restrict__ g2)
{
    int tid = threadIdx.x & 63;
    int node = blockIdx.x * 4 + (threadIdx.x >> 6);
    int base = node & ~(NN - 1);
    float wa = w2g[2 * tid], wb = w2g[2 * tid + 1];
    int c = cnt[node];
    const int* ec = ecol + (size_t)node * ELLW;
    const float* ev = eval_ + (size_t)node * ELLW;
    const __half2* g1v = (const __half2*)g1;
    float aa = 0.f, ab = 0.f;
    int s = 0;
    for (; s + 4 <= c; s += 4) {
        int j0 = ec[s], j1 = ec[s + 1], j2 = ec[s + 2], j3 = ec[s + 3];
        float v0 = ev[s], v1 = ev[s + 1], v2 = ev[s + 2], v3 = ev[s + 3];
        __half2 u0 = g1v[((size_t)(base + j0)) * 64 + tid];
        __half2 u1 = g1v[((size_t)(base + j1)) * 64 + tid];
        __half2 u2 = g1v[((size_t)(base + j2)) * 64 + tid];
        __half2 u3 = g1v[((size_t)(base + j3)) * 64 + tid];
        aa = fmaf(v0, __low2float(u0), aa); ab = fmaf(v0, __high2float(u0), ab);
        aa = fmaf(v1, __low2float(u1), aa); ab = fmaf(v1, __high2float(u1), ab);
        aa = fmaf(v2, __low2float(u2), aa); ab = fmaf(v2, __high2float(u2), ab);
        aa = fmaf(v3, __low2float(u3), aa); ab = fmaf(v3, __high2float(u3), ab);
    }
    for (; s < c; ++s) {
        __half2 u = g1v[((size_t)(base + ec[s])) * 64 + tid];
        float v = ev[s];
        aa = fmaf(v, __low2float(u), aa); ab = fmaf(v, __high2float(u), ab);
    }
    float h1a = aa > 0.f ? aa : 0.2f * aa;
    float h1b = ab > 0.f ? ab : 0.2f * ab;
    float p = h1a * wa + h1b * wb;
    #pragma unroll
    for (int off = 32; off >= 1; off >>= 1) p += __shfl_down(p, off, 64);
    if (tid == 0) g2[node] = p;
}

// ------------- stage 6: out = sigmoid(adj @ g2) (4 nodes/block) ----------
__global__ __launch_bounds__(256) void k_spmm2(
    const float* __restrict__ g2, const int* __restrict__ cnt,
    const int* __restrict__ ecol, const float* __restrict__ eval_,
    float* __restrict__ out)
{
    int lane = threadIdx.x & 63;
    int node = blockIdx.x * 4 + (threadIdx.x >> 6);
    int base = node & ~(NN - 1);
    int c = cnt[node];
    float p = 0.f;
    if (lane < c) {
        int j = ecol[(size_t)node * ELLW + lane];
        p = eval_[(size_t)node * ELLW + lane] * g2[base + j];
    }
    #pragma unroll
    for (int off = 32; off >= 1; off >>= 1) p += __shfl_down(p, off, 64);
    if (lane == 0) out[node] = 1.f / (1.f + __expf(-p));
}

extern "C" void kernel_launch(void* const* d_in, const int* in_sizes, int n_in,
                              void* d_out, int out_size, void* d_ws, size_t ws_size,
                              hipStream_t stream)
{
    const float* search = (const float*)d_in[0];
    const float* xcorr  = (const float*)d_in[1];
    const int*   pairs  = (const int*)d_in[2];
    const float* w1     = (const float*)d_in[3];
    const float* b1     = (const float*)d_in[4];
    const float* gamma  = (const float*)d_in[5];
    const float* beta   = (const float*)d_in[6];
    const float* w2     = (const float*)d_in[7];
    const float* b2     = (const float*)d_in[8];
    const float* gc1w   = (const float*)d_in[9];
    const float* gc2w   = (const float*)d_in[10];
    float* out = (float*)d_out;

    int E   = in_sizes[2] / (BB * 2);    // 10068
    int EKP = E - NENG;                  // 2256 keypoint-clique edges
    int nbU  = (NUD + 255) / 256;        // 20 undirected-edge tiles
    int nGC  = BB * 32;                  // 512 gc1 blocks

    char* ws = (char*)d_ws;
    size_t off = 0;
    auto alloc = [&](size_t bytes) {
        size_t o = off;
        off += (bytes + 255) & ~(size_t)255;
        return o;
    };
    __bf16* whi   = (__bf16*)(ws + alloc(10 * 4 * 64 * 8 * 2));   // 40960 B
    __bf16* wlo   = (__bf16*)(ws + alloc(10 * 4 * 64 * 8 * 2));   // contiguous after whi
    __bf16* gwhi  = (__bf16*)(ws + alloc(10 * 8 * 64 * 8 * 2));
    __bf16* gwlo  = (__bf16*)(ws + alloc(10 * 8 * 64 * 8 * 2));
    float* featT  = (float*)(ws + alloc((size_t)BB * NN * CC * 4));
    bf16*  hstore = (bf16*)(ws + alloc((size_t)BB * E * PH * 2));
    float* Ssum   = (float*)(ws + alloc(BB * PH * 4));
    float* S2sum  = (float*)(ws + alloc(BB * PH * 4));
    int*   cnt    = (int*)(ws + alloc(BB * NN * 4));
    int*   ecol   = (int*)(ws + alloc((size_t)BB * NN * ELLW * 4));
    float* eval_  = (float*)(ws + alloc((size_t)BB * NN * ELLW * 4));
    __half* g1    = (__half*)(ws + alloc((size_t)BB * NN * GH * 2));
    float* g2     = (float*)(ws + alloc(BB * NN * 4));
    (void)ws_size; (void)n_in; (void)out_size;

    k_prep_transpose<<<dim3(BB * 320 + 160), dim3(256), 0, stream>>>(
        search, xcorr, featT, w1, gc1w, whi, wlo, gwhi, gwlo, cnt, Ssum, S2sum);
    k_edge<<<dim3(1024 + BB * 18), dim3(256), 0, stream>>>(featT, pairs, whi, b1,
                                                           hstore, Ssum, S2sum,
                                                           E, EKP);
    k_val_gc1<<<dim3(nGC + BB * nbU), dim3(256), 0, stream>>>(
        featT, gwhi, gwlo, g1, hstore, Ssum, S2sum, gamma, beta, w2, b2,
        pairs, cnt, ecol, eval_, E, EKP, nGC);
    k_spmm1<<<dim3(BB * NN / 4), dim3(256), 0, stream>>>(g1, cnt, ecol, eval_,
                                                         gc2w, g2);
    k_spmm2<<<dim3(BB * NN / 4), dim3(256), 0, stream>>>(g2, cnt, ecol, eval_, out);
}

// Round 9
// 169.714 us; speedup vs baseline: 1.0139x; 1.0139x over previous
//
#include <hip/hip_runtime.h>
#include <hip/hip_bf16.h>
#include <hip/hip_fp16.h>

#define BB 16
#define NN 1024
#define CS 256
#define CX 64
#define CC 320
#define PH 64
#define GH 128
#define ELLW 64
#define NENG 7812   // 8-neigh edges per image (H=W=32)
#define NKPH 1128   // kp half-pairs (a<y)
#define NGU  3906   // undirected ng edges (forward dirs 0..3)
#define NUD  5034   // total undirected edges per image (NKPH + NGU)

typedef __hip_bfloat16 bf16;
typedef __attribute__((ext_vector_type(8))) __bf16 bfrag;   // 8 bf16 = 4 VGPRs
typedef __attribute__((ext_vector_type(4))) float v4f;

// triangular decode: m in [0,1128) -> pair (a,y), a<y, kp slots 0..47
__device__ __forceinline__ void tri_decode(int m, int& a, int& y) {
    float s = sqrtf((float)(9025 - 8 * m));
    int aa = (int)((95.0f - s) * 0.5f);
    if (aa > 0 && 47 * aa - (aa * (aa - 1)) / 2 > m) --aa;
    while (47 * (aa + 1) - ((aa + 1) * aa) / 2 <= m) ++aa;
    a = aa;
    y = aa + 1 + (m - (47 * aa - (aa * (aa - 1)) / 2));
}

// ---- merged prep (W packing, zero-init) + transpose [B,C,N]->[B,N,C] ----
__global__ __launch_bounds__(256) void k_prep_transpose(
    const float* __restrict__ search, const float* __restrict__ xcorr,
    float* __restrict__ featT,
    const float* __restrict__ w1, const float* __restrict__ gc1w,
    __bf16* __restrict__ whi, __bf16* __restrict__ wlo,
    __bf16* __restrict__ gwhi, __bf16* __restrict__ gwlo,
    int* __restrict__ cnt, float* __restrict__ Ssum, float* __restrict__ S2sum)
{
    __shared__ float tile[32][33];
    int blk = blockIdx.x;
    int tid = threadIdx.x;
    if (blk < BB * 320) {
        int b   = blk % BB;
        int rem = blk / BB;       // 0..319
        int ct  = rem >> 5;       // 10 channel tiles
        int ntl = rem & 31;       // 32 node tiles
        int cl = tid >> 5, nl = tid & 31;
        const float* sb = search + (size_t)b * CS * NN;
        const float* xb = xcorr + (size_t)b * CX * NN;
        #pragma unroll
        for (int f = 0; f < 4; ++f) {
            int c = ct * 32 + cl + f * 8;
            int n = ntl * 32 + nl;
            float v = (c < CS) ? sb[(size_t)c * NN + n] : xb[(size_t)(c - CS) * NN + n];
            tile[cl + f * 8][nl] = v;
        }
        __syncthreads();
        #pragma unroll
        for (int f = 0; f < 4; ++f) {
            int nr = cl + f * 8;
            int cc = nl;
            featT[((size_t)b * NN + ntl * 32 + nr) * CC + ct * 32 + cc] = tile[cc][nr];
        }
    } else {
        int idx = (blk - BB * 320) * 256 + tid;
        if (idx < 10 * 4 * 64 * 8) {          // W1: PH=64 -> 4 ntiles
            int j    = idx & 7;
            int lane = (idx >> 3) & 63;
            int nt   = (idx >> 9) & 3;
            int ks   = idx >> 11;
            int k = ks * 32 + (lane >> 4) * 8 + j;
            int n = nt * 16 + (lane & 15);
            float w = w1[k * PH + n];
            __bf16 h = (__bf16)w;
            whi[idx] = h;
            wlo[idx] = (__bf16)(w - (float)h);
        }
        if (idx < 10 * 8 * 64 * 8) {          // gc1_w: GH=128 -> 8 ntiles
            int j    = idx & 7;
            int lane = (idx >> 3) & 63;
            int nt   = (idx >> 9) & 7;
            int ks   = idx >> 12;
            int k = ks * 32 + (lane >> 4) * 8 + j;
            int n = nt * 16 + (lane & 15);
            float w = gc1w[k * GH + n];
            __bf16 h = (__bf16)w;
            gwhi[idx] = h;
            gwlo[idx] = (__bf16)(w - (float)h);
        }
        if (idx < BB * NN) cnt[idx] = 0;
        if (idx < BB * PH) { Ssum[idx] = 0.f; S2sum[idx] = 0.f; }
    }
}

// ------ stage 1: fine-grained no-LDS edge kernel, MLP-forced.
//   1312 blocks x 256 thr, launch_bounds(256,2) -> ~214 VGPR, 8 waves/CU,
//   40 outstanding float4 loads per wave (preloaded A-fragments).
//   Blocks [0,1024): ng — b = blk&15 (XCD-interleaved), unit = blk>>4.
//   Blocks [1024,1312): kp — b-uniform, u = (kblk%18)*4+wave.
__global__ __launch_bounds__(256, 2) void k_edge(
    const float* __restrict__ featT, const int* __restrict__ pairs,
    const __bf16* __restrict__ wglob, const float* __restrict__ b1,
    bf16* __restrict__ hstore, float* __restrict__ Ssum,
    float* __restrict__ S2sum, int E, int EKP)
{
    __shared__ float sS[PH];
    __shared__ float sS2[PH];

    int t = threadIdx.x;
    int wave = t >> 6, lane = t & 63;
    int q = lane >> 4, r = lane & 15;

    const bfrag* WH = (const bfrag*)wglob;          // 2560 fragments (40 KB)
    const bfrag* WL = WH + 2560;                    // lo half

    float b1v[4];
    #pragma unroll
    for (int nt = 0; nt < 4; ++nt) b1v[nt] = b1[nt * 16 + r];
    float ps[4], ps2[4];
    #pragma unroll
    for (int nt = 0; nt < 4; ++nt) { ps[nt] = 0.f; ps2[nt] = 0.f; }
    int b;

    if (blockIdx.x < 1024) {
        // ---------------- ng branch: wave-unit (b, y, d, mt) --------------
        b = blockIdx.x & 15;
        int u2 = blockIdx.x >> 4;         // 0..63
        int mt = u2 >> 5;                 // 0..1
        int d  = (u2 >> 3) & 3;           // 0..3
        int y  = ((u2 & 7) << 2) + wave;  // 0..31

        const int dyT[4] = {-1,-1,-1, 0};
        const int dxT[4] = {-1, 0, 1,-1};
        const int pfT4[4] = {0, 961, 1953, 2914};
        int dy = dyT[d], dx = dxT[d];
        int y0 = dy < 0 ? 1 : 0;
        int x0 = dx < 0 ? 1 : 0;
        int ww = (dx == 0) ? 32 : 31;
        int pfF = pfT4[d];

        int xiL = mt * 16 + r;
        int ni = y * 32 + xiL;
        int xj = xiL + dx; xj = xj < 0 ? 0 : (xj > 31 ? 31 : xj);
        int gy = y + dy; int gyc = gy < 0 ? 0 : gy;
        int nj = gyc * 32 + xj;
        const float* rI = featT + ((size_t)b * NN + ni) * CC + q * 8;
        const float* rJ = featT + ((size_t)b * NN + nj) * CC + q * 8;

        // ---- issue ALL 40 loads up-front: 40-deep MLP per wave ----
        float4 fA[20], fB[20];
        #pragma unroll
        for (int ks = 0; ks < 10; ++ks) {
            fA[2 * ks]     = *(const float4*)(rI + ks * 32);
            fA[2 * ks + 1] = *(const float4*)(rI + ks * 32 + 4);
            fB[2 * ks]     = *(const float4*)(rJ + ks * 32);
            fB[2 * ks + 1] = *(const float4*)(rJ + ks * 32 + 4);
        }

        v4f acc[4];
        #pragma unroll
        for (int nt = 0; nt < 4; ++nt) acc[nt] = (v4f)0.f;

        #pragma unroll
        for (int ks = 0; ks < 10; ++ks) {
            float df[8];
            df[0] = fabsf(fA[2*ks].x - fB[2*ks].x);
            df[1] = fabsf(fA[2*ks].y - fB[2*ks].y);
            df[2] = fabsf(fA[2*ks].z - fB[2*ks].z);
            df[3] = fabsf(fA[2*ks].w - fB[2*ks].w);
            df[4] = fabsf(fA[2*ks+1].x - fB[2*ks+1].x);
            df[5] = fabsf(fA[2*ks+1].y - fB[2*ks+1].y);
            df[6] = fabsf(fA[2*ks+1].z - fB[2*ks+1].z);
            df[7] = fabsf(fA[2*ks+1].w - fB[2*ks+1].w);

            bfrag ah, al;
            #pragma unroll
            for (int kk = 0; kk < 8; ++kk) {
                __bf16 h = (__bf16)df[kk];
                ah[kk] = h;
                al[kk] = (__bf16)(df[kk] - (float)h);
            }
            #pragma unroll
            for (int nt = 0; nt < 4; ++nt) {
                bfrag bh = WH[((ks * 4 + nt) << 6) + lane];
                bfrag bl = WL[((ks * 4 + nt) << 6) + lane];
                acc[nt] = __builtin_amdgcn_mfma_f32_16x16x32_bf16(ah, bh, acc[nt], 0, 0, 0);
                acc[nt] = __builtin_amdgcn_mfma_f32_16x16x32_bf16(ah, bl, acc[nt], 0, 0, 0);
                acc[nt] = __builtin_amdgcn_mfma_f32_16x16x32_bf16(al, bh, acc[nt], 0, 0, 0);
            }
        }

        // ng store (FORWARD only) + BN stats
        #pragma unroll
        for (int reg = 0; reg < 4; ++reg) {
            int xi = mt * 16 + q * 4 + reg;
            int y2 = y + dy, x2 = xi + dx;
            bool valid = ((unsigned)y2 < 32u) && ((unsigned)x2 < 32u);
            if (valid) {
                int e1 = EKP + pfF + (y - y0) * ww + (xi - x0);
                bf16* h1 = hstore + ((size_t)b * E + e1) * PH + r;
                #pragma unroll
                for (int nt = 0; nt < 4; ++nt) {
                    float v = acc[nt][reg] + b1v[nt];
                    h1[nt * 16] = __float2bfloat16(v);
                    ps[nt] += v;
                    ps2[nt] = fmaf(v, v, ps2[nt]);
                }
            }
        }
    } else {
        // ---------------- kp branch: b-uniform blocks ---------------------
        int kblk = blockIdx.x - 1024;     // 0..287
        b = kblk / 18;
        int u = (kblk % 18) * 4 + wave;   // 0..71; u==71 idle
        if (u < 71) {
            int mA = u * 16 + r;
            if (mA >= NKPH) mA = NKPH - 1;
            int aI, yI;
            tri_decode(mA, aI, yI);
            int na = pairs[((size_t)b * E + aI * 47) * 2];
            int ny = pairs[((size_t)b * E + yI * 47) * 2];
            const float* rI = featT + ((size_t)b * NN + na) * CC + q * 8;
            const float* rJ = featT + ((size_t)b * NN + ny) * CC + q * 8;

            float4 fA[20], fB[20];
            #pragma unroll
            for (int ks = 0; ks < 10; ++ks) {
                fA[2 * ks]     = *(const float4*)(rI + ks * 32);
                fA[2 * ks + 1] = *(const float4*)(rI + ks * 32 + 4);
                fB[2 * ks]     = *(const float4*)(rJ + ks * 32);
                fB[2 * ks + 1] = *(const float4*)(rJ + ks * 32 + 4);
            }

            v4f acc2[4];
            #pragma unroll
            for (int nt = 0; nt < 4; ++nt) acc2[nt] = (v4f)0.f;

            #pragma unroll
            for (int ks = 0; ks < 10; ++ks) {
                float df[8];
                df[0] = fabsf(fA[2*ks].x - fB[2*ks].x);
                df[1] = fabsf(fA[2*ks].y - fB[2*ks].y);
                df[2] = fabsf(fA[2*ks].z - fB[2*ks].z);
                df[3] = fabsf(fA[2*ks].w - fB[2*ks].w);
                df[4] = fabsf(fA[2*ks+1].x - fB[2*ks+1].x);
                df[5] = fabsf(fA[2*ks+1].y - fB[2*ks+1].y);
                df[6] = fabsf(fA[2*ks+1].z - fB[2*ks+1].z);
                df[7] = fabsf(fA[2*ks+1].w - fB[2*ks+1].w);

                bfrag ah, al;
                #pragma unroll
                for (int kk = 0; kk < 8; ++kk) {
                    __bf16 h = (__bf16)df[kk];
                    ah[kk] = h;
                    al[kk] = (__bf16)(df[kk] - (float)h);
                }
                #pragma unroll
                for (int nt = 0; nt < 4; ++nt) {
                    bfrag bh = WH[((ks * 4 + nt) << 6) + lane];
                    bfrag bl = WL[((ks * 4 + nt) << 6) + lane];
                    acc2[nt] = __builtin_amdgcn_mfma_f32_16x16x32_bf16(ah, bh, acc2[nt], 0, 0, 0);
                    acc2[nt] = __builtin_amdgcn_mfma_f32_16x16x32_bf16(ah, bl, acc2[nt], 0, 0, 0);
                    acc2[nt] = __builtin_amdgcn_mfma_f32_16x16x32_bf16(al, bh, acc2[nt], 0, 0, 0);
                }
            }

            #pragma unroll
            for (int reg = 0; reg < 4; ++reg) {
                int mC = u * 16 + q * 4 + reg;
                if (mC < NKPH) {
                    int a, yk;
                    tri_decode(mC, a, yk);
                    int e1 = a * 47 + yk - 1;    // forward (a,yk), a<yk
                    bf16* h1 = hstore + ((size_t)b * E + e1) * PH + r;
                    #pragma unroll
                    for (int nt = 0; nt < 4; ++nt) {
                        float v = acc2[nt][reg] + b1v[nt];
                        h1[nt * 16] = __float2bfloat16(v);
                        ps[nt] += v;
                        ps2[nt] = fmaf(v, v, ps2[nt]);
                    }
                }
            }
        }
    }

    // common BN reduce: cross-lane q-sum, LDS atomics, global atomics.
    // x2 for symmetric duplicate edges.
    if (t < PH) { sS[t] = 0.f; sS2[t] = 0.f; }
    __syncthreads();
    #pragma unroll
    for (int nt = 0; nt < 4; ++nt) {
        float p1 = ps[nt]  + __shfl_xor(ps[nt], 16, 64);
        p1 += __shfl_xor(p1, 32, 64);
        float p2 = ps2[nt] + __shfl_xor(ps2[nt], 16, 64);
        p2 += __shfl_xor(p2, 32, 64);
        if (lane < 16) {
            atomicAdd(&sS[nt * 16 + r],  2.0f * p1);
            atomicAdd(&sS2[nt * 16 + r], 2.0f * p2);
        }
    }
    __syncthreads();
    if (t < PH) {
        atomicAdd(&Ssum[b * PH + t],  sS[t]);
        atomicAdd(&S2sum[b * PH + t], sS2[t]);
    }
}

// -- merged: gc1 (blocks [0,512)) + BN-final/edge-val over UNDIRECTED edges
//    (blocks [512, 512+16*20)): one h read + sigmoid per undirected edge,
//    scatter BOTH ELL directions.  g1 stored as FP16 (halves spmm1 gather).
__global__ __launch_bounds__(256, 2) void k_val_gc1(
    const float* __restrict__ featT, const __bf16* __restrict__ gwhi,
    const __bf16* __restrict__ gwlo, __half* __restrict__ g1,
    const bf16* __restrict__ hstore, const float* __restrict__ Ssum,
    const float* __restrict__ S2sum, const float* __restrict__ gamma,
    const float* __restrict__ beta, const float* __restrict__ w2,
    const float* __restrict__ b2, const int* __restrict__ pairs,
    int* __restrict__ cnt, int* __restrict__ ecol, float* __restrict__ eval_,
    int E, int EKP, int nGC)
{
    __shared__ ushort WG[40960];   // 80 KB (gc1); edge_val reuses <1 KB of it

    int t = threadIdx.x;
    if ((int)blockIdx.x < nGC) {
        // -------------------- gc1 branch --------------------
        int b = blockIdx.x % BB;
        int rem = blockIdx.x / BB;     // 0..31
        int half = rem & 1;
        int m0 = b * NN + (rem >> 1) * 64;

        {
            uint4* dst = (uint4*)WG;
            const uint4* sh = (const uint4*)gwhi;
            const uint4* sl = (const uint4*)gwlo;
            #pragma unroll
            for (int k = 0; k < 10; ++k) {
                int u = t + k * 256;
                int chunk = u >> 6, v = u & 63;
                int ks = chunk >> 2, ntp = chunk & 3;
                int src = (ks * 8 + half * 4 + ntp) * 64 + v;
                dst[u]        = sh[src];
                dst[2560 + u] = sl[src];
            }
        }

        int wave = t >> 6, lane = t & 63;
        int q = lane >> 4, r = lane & 15;
        const float* fp = featT + (size_t)(m0 + wave * 16 + r) * CC + q * 8;

        float fa[2][8];
        auto LOADA = [&](int ks, int buf) {
            const float4* p = (const float4*)(fp + ks * 32);
            *(float4*)&fa[buf][0] = p[0];
            *(float4*)&fa[buf][4] = p[1];
        };

        v4f acc[4];
        #pragma unroll
        for (int nt = 0; nt < 4; ++nt) acc[nt] = (v4f)0.f;

        LOADA(0, 0);
        __syncthreads();

        const bfrag* WGH = (const bfrag*)WG;
        const bfrag* WGL = (const bfrag*)(WG + 20480);

        #pragma unroll
        for (int ks = 0; ks < 10; ++ks) {
            int cur = ks & 1;
            if (ks < 9) LOADA(ks + 1, cur ^ 1);
            bfrag ah, al;
            #pragma unroll
            for (int kk = 0; kk < 8; ++kk) {
                float d = fa[cur][kk];
                __bf16 h = (__bf16)d;
                ah[kk] = h;
                al[kk] = (__bf16)(d - (float)h);
            }
            #pragma unroll
            for (int nt = 0; nt < 4; ++nt) {
                bfrag bh = WGH[((ks * 4 + nt) << 6) + lane];
                bfrag bl = WGL[((ks * 4 + nt) << 6) + lane];
                acc[nt] = __builtin_amdgcn_mfma_f32_16x16x32_bf16(ah, bh, acc[nt], 0, 0, 0);
                acc[nt] = __builtin_amdgcn_mfma_f32_16x16x32_bf16(ah, bl, acc[nt], 0, 0, 0);
                acc[nt] = __builtin_amdgcn_mfma_f32_16x16x32_bf16(al, bh, acc[nt], 0, 0, 0);
            }
        }
        #pragma unroll
        for (int nt = 0; nt < 4; ++nt) {
            #pragma unroll
            for (int reg = 0; reg < 4; ++reg) {
                int m = m0 + wave * 16 + q * 4 + reg;
                g1[(size_t)m * GH + (half * 4 + nt) * 16 + r] =
                    __float2half(acc[nt][reg]);
            }
        }
    } else {
        // ---------- edge_val branch: undirected edges, dual scatter --------
        float* ca = (float*)WG;
        float* cb = ca + PH;
        int* kpl = (int*)(cb + PH);
        int blk = blockIdx.x - nGC;
        int b = blk % BB;
        int u = (blk / BB) * 256 + t;
        if (t < PH) {
            int l = t;
            float mu = Ssum[b * PH + l] / E;
            float var = S2sum[b * PH + l] / E - mu * mu;
            float A = rsqrtf(var + 1e-5f) * gamma[l];
            ca[l] = A;
            cb[l] = beta[l] - mu * A;
        }
        if (t < 48) kpl[t] = pairs[((size_t)b * E + t * 47) * 2];
        __syncthreads();
        if (u >= NUD) return;

        int i, j, hrow;
        if (u < NKPH) {
            int a, yk;
            tri_decode(u, a, yk);
            i = kpl[a]; j = kpl[yk];
            hrow = a * 47 + yk - 1;
        } else {
            int up = u - NKPH;           // [0, 3906) forward-region offset
            int pf, ww, y0, x0, dy, dx;
            if (up < 961)       { pf = 0;    ww = 31; y0 = 1; x0 = 1; dy = -1; dx = -1; }
            else if (up < 1953) { pf = 961;  ww = 32; y0 = 1; x0 = 0; dy = -1; dx = 0;  }
            else if (up < 2914) { pf = 1953; ww = 31; y0 = 1; x0 = 0; dy = -1; dx = 1;  }
            else                { pf = 2914; ww = 31; y0 = 0; x0 = 1; dy = 0;  dx = -1; }
            int rel = up - pf;
            int yR = rel / ww, xC = rel - yR * ww;
            int yy = yR + y0, xi = xC + x0;
            i = yy * 32 + xi;
            j = (yy + dy) * 32 + (xi + dx);
            hrow = EKP + up;             // undirected ng id == forward hstore offset
        }

        const bfrag* hp = (const bfrag*)(hstore + ((size_t)b * E + hrow) * PH);
        float acc = 0.f;
        #pragma unroll
        for (int l8 = 0; l8 < 8; ++l8) {
            bfrag hv = hp[l8];
            #pragma unroll
            for (int c = 0; c < 8; ++c) {
                int l = l8 * 8 + c;
                float x = fmaf((float)hv[c], ca[l], cb[l]);
                x = x > 0.f ? x : 0.f;
                acc = fmaf(x, w2[l], acc);
            }
        }
        float edge = 1.f / (1.f + __expf(-(acc + b2[0])));
        int ri = b * NN + i;
        int rj = b * NN + j;
        int s1 = atomicAdd(&cnt[ri], 1);
        if (s1 < ELLW) {
            ecol[ri * ELLW + s1]  = j;
            eval_[ri * ELLW + s1] = edge;
        }
        int s2 = atomicAdd(&cnt[rj], 1);
        if (s2 < ELLW) {
            ecol[rj * ELLW + s2]  = i;
            eval_[rj * ELLW + s2] = edge;
        }
    }
}

// ------- stage 5: g2 = (leaky(adj@g1)) @ gc2_w  (4 nodes/block, f16 g1) --
__global__ __launch_bounds__(256) void k_spmm1(
    const __half* __restrict__ g1, const int* __restrict__ cnt,
    const int* __restrict__ ecol, const float* __restrict__ eval_,
    const float* __restrict__ w2g, float* __restrict__ g2)
{
    int tid = threadIdx.x & 63;
    int node = blockIdx.x * 4 + (threadIdx.x >> 6);
    int base = node & ~(NN - 1);
    float wa = w2g[2 * tid], wb = w2g[2 * tid + 1];
    int c = cnt[node];
    const int* ec = ecol + (size_t)node * ELLW;
    const float* ev = eval_ + (size_t)node * ELLW;
    const __half2* g1v = (const __half2*)g1;
    float aa = 0.f, ab = 0.f;
    int s = 0;
    for (; s + 4 <= c; s += 4) {
        int j0 = ec[s], j1 = ec[s + 1], j2 = ec[s + 2], j3 = ec[s + 3];
        float v0 = ev[s], v1 = ev[s + 1], v2 = ev[s + 2], v3 = ev[s + 3];
        __half2 u0 = g1v[((size_t)(base + j0)) * 64 + tid];
        __half2 u1 = g1v[((size_t)(base + j1)) * 64 + tid];
        __half2 u2 = g1v[((size_t)(base + j2)) * 64 + tid];
        __half2 u3 = g1v[((size_t)(base + j3)) * 64 + tid];
        aa = fmaf(v0, __low2float(u0), aa); ab = fmaf(v0, __high2float(u0), ab);
        aa = fmaf(v1, __low2float(u1), aa); ab = fmaf(v1, __high2float(u1), ab);
        aa = fmaf(v2, __low2float(u2), aa); ab = fmaf(v2, __high2float(u2), ab);
        aa = fmaf(v3, __low2float(u3), aa); ab = fmaf(v3, __high2float(u3), ab);
    }
    for (; s < c; ++s) {
        __half2 u = g1v[((size_t)(base + ec[s])) * 64 + tid];
        float v = ev[s];
        aa = fmaf(v, __low2float(u), aa); ab = fmaf(v, __high2float(u), ab);
    }
    float h1a = aa > 0.f ? aa : 0.2f * aa;
    float h1b = ab > 0.f ? ab : 0.2f * ab;
    float p = h1a * wa + h1b * wb;
    #pragma unroll
    for (int off = 32; off >= 1; off >>= 1) p += __shfl_down(p, off, 64);
    if (tid == 0) g2[node] = p;
}

// ------------- stage 6: out = sigmoid(adj @ g2) (4 nodes/block) ----------
__global__ __launch_bounds__(256) void k_spmm2(
    const float* __restrict__ g2, const int* __restrict__ cnt,
    const int* __restrict__ ecol, const float* __restrict__ eval_,
    float* __restrict__ out)
{
    int lane = threadIdx.x & 63;
    int node = blockIdx.x * 4 + (threadIdx.x >> 6);
    int base = node & ~(NN - 1);
    int c = cnt[node];
    float p = 0.f;
    if (lane < c) {
        int j = ecol[(size_t)node * ELLW + lane];
        p = eval_[(size_t)node * ELLW + lane] * g2[base + j];
    }
    #pragma unroll
    for (int off = 32; off >= 1; off >>= 1) p += __shfl_down(p, off, 64);
    if (lane == 0) out[node] = 1.f / (1.f + __expf(-p));
}

extern "C" void kernel_launch(void* const* d_in, const int* in_sizes, int n_in,
                              void* d_out, int out_size, void* d_ws, size_t ws_size,
                              hipStream_t stream)
{
    const float* search = (const float*)d_in[0];
    const float* xcorr  = (const float*)d_in[1];
    const int*   pairs  = (const int*)d_in[2];
    const float* w1     = (const float*)d_in[3];
    const float* b1     = (const float*)d_in[4];
    const float* gamma  = (const float*)d_in[5];
    const float* beta   = (const float*)d_in[6];
    const float* w2     = (const float*)d_in[7];
    const float* b2     = (const float*)d_in[8];
    const float* gc1w   = (const float*)d_in[9];
    const float* gc2w   = (const float*)d_in[10];
    float* out = (float*)d_out;

    int E   = in_sizes[2] / (BB * 2);    // 10068
    int EKP = E - NENG;                  // 2256 keypoint-clique edges
    int nbU  = (NUD + 255) / 256;        // 20 undirected-edge tiles
    int nGC  = BB * 32;                  // 512 gc1 blocks

    char* ws = (char*)d_ws;
    size_t off = 0;
    auto alloc = [&](size_t bytes) {
        size_t o = off;
        off += (bytes + 255) & ~(size_t)255;
        return o;
    };
    __bf16* whi   = (__bf16*)(ws + alloc(10 * 4 * 64 * 8 * 2));   // 40960 B
    __bf16* wlo   = (__bf16*)(ws + alloc(10 * 4 * 64 * 8 * 2));   // contiguous after whi
    __bf16* gwhi  = (__bf16*)(ws + alloc(10 * 8 * 64 * 8 * 2));
    __bf16* gwlo  = (__bf16*)(ws + alloc(10 * 8 * 64 * 8 * 2));
    float* featT  = (float*)(ws + alloc((size_t)BB * NN * CC * 4));
    bf16*  hstore = (bf16*)(ws + alloc((size_t)BB * E * PH * 2));
    float* Ssum   = (float*)(ws + alloc(BB * PH * 4));
    float* S2sum  = (float*)(ws + alloc(BB * PH * 4));
    int*   cnt    = (int*)(ws + alloc(BB * NN * 4));
    int*   ecol   = (int*)(ws + alloc((size_t)BB * NN * ELLW * 4));
    float* eval_  = (float*)(ws + alloc((size_t)BB * NN * ELLW * 4));
    __half* g1    = (__half*)(ws + alloc((size_t)BB * NN * GH * 2));
    float* g2     = (float*)(ws + alloc(BB * NN * 4));
    (void)ws_size; (void)n_in; (void)out_size;

    k_prep_transpose<<<dim3(BB * 320 + 160), dim3(256), 0, stream>>>(
        search, xcorr, featT, w1, gc1w, whi, wlo, gwhi, gwlo, cnt, Ssum, S2sum);
    k_edge<<<dim3(1024 + BB * 18), dim3(256), 0, stream>>>(featT, pairs, whi, b1,
                                                           hstore, Ssum, S2sum,
                                                           E, EKP);
    k_val_gc1<<<dim3(nGC + BB * nbU), dim3(256), 0, stream>>>(
        featT, gwhi, gwlo, g1, hstore, Ssum, S2sum, gamma, beta, w2, b2,
        pairs, cnt, ecol, eval_, E, EKP, nGC);
    k_spmm1<<<dim3(BB * NN / 4), dim3(256), 0, stream>>>(g1, cnt, ecol, eval_,
                                                         gc2w, g2);
    k_spmm2<<<dim3(BB * NN / 4), dim3(256), 0, stream>>>(g2, cnt, ecol, eval_, out);
}

// Round 10
// 150.066 us; speedup vs baseline: 1.1467x; 1.1309x over previous
//
#include <hip/hip_runtime.h>
#include <hip/hip_bf16.h>
#include <hip/hip_fp16.h>

#define BB 16
#define NN 1024
#define CS 256
#define CX 64
#define CC 320
#define PH 64
#define GH 128
#define ELLW 64
#define NENG 7812   // 8-neigh edges per image (H=W=32)
#define ROWP 324    // padded kp row stride in floats (320 + 4)
#define RSTR 164    // ng LDS row stride in floats (160 + 4); (4r+8q)%32 -> 2-way only
#define NKPH 1128   // kp half-pairs (a<y)
#define NGU  3906   // undirected ng edges (forward dirs 0..3)
#define NUD  5034   // total undirected edges per image (NKPH + NGU)

typedef __hip_bfloat16 bf16;
typedef __attribute__((ext_vector_type(8))) __bf16 bfrag;   // 8 bf16 = 4 VGPRs
typedef __attribute__((ext_vector_type(4))) float v4f;

// triangular decode: m in [0,1128) -> pair (a,y), a<y, kp slots 0..47
__device__ __forceinline__ void tri_decode(int m, int& a, int& y) {
    float s = sqrtf((float)(9025 - 8 * m));
    int aa = (int)((95.0f - s) * 0.5f);
    if (aa > 0 && 47 * aa - (aa * (aa - 1)) / 2 > m) --aa;
    while (47 * (aa + 1) - ((aa + 1) * aa) / 2 <= m) ++aa;
    a = aa;
    y = aa + 1 + (m - (47 * aa - (aa * (aa - 1)) / 2));
}

// ---- merged prep (W packing, zero-init) + transpose [B,C,N]->[B,N,C] ----
// blocks [0, 5120): transpose; blocks [5120, 5280): prep.
__global__ __launch_bounds__(256) void k_prep_transpose(
    const float* __restrict__ search, const float* __restrict__ xcorr,
    float* __restrict__ featT,
    const float* __restrict__ w1, const float* __restrict__ gc1w,
    __bf16* __restrict__ whi, __bf16* __restrict__ wlo,
    __bf16* __restrict__ gwhi, __bf16* __restrict__ gwlo,
    int* __restrict__ cnt, float* __restrict__ Ssum, float* __restrict__ S2sum)
{
    __shared__ float tile[32][33];
    int blk = blockIdx.x;
    int tid = threadIdx.x;
    if (blk < BB * 320) {
        // ---------------- transpose branch ----------------
        int b   = blk % BB;
        int rem = blk / BB;       // 0..319
        int ct  = rem >> 5;       // 10 channel tiles
        int ntl = rem & 31;       // 32 node tiles
        int cl = tid >> 5, nl = tid & 31;
        const float* sb = search + (size_t)b * CS * NN;
        const float* xb = xcorr + (size_t)b * CX * NN;
        #pragma unroll
        for (int f = 0; f < 4; ++f) {
            int c = ct * 32 + cl + f * 8;
            int n = ntl * 32 + nl;
            float v = (c < CS) ? sb[(size_t)c * NN + n] : xb[(size_t)(c - CS) * NN + n];
            tile[cl + f * 8][nl] = v;
        }
        __syncthreads();
        #pragma unroll
        for (int f = 0; f < 4; ++f) {
            int nr = cl + f * 8;
            int cc = nl;
            featT[((size_t)b * NN + ntl * 32 + nr) * CC + ct * 32 + cc] = tile[cc][nr];
        }
    } else {
        // ---------------- prep branch ----------------
        int idx = (blk - BB * 320) * 256 + tid;
        if (idx < 10 * 4 * 64 * 8) {          // W1: PH=64 -> 4 ntiles
            int j    = idx & 7;
            int lane = (idx >> 3) & 63;
            int nt   = (idx >> 9) & 3;
            int ks   = idx >> 11;
            int k = ks * 32 + (lane >> 4) * 8 + j;
            int n = nt * 16 + (lane & 15);
            float w = w1[k * PH + n];
            __bf16 h = (__bf16)w;
            whi[idx] = h;
            wlo[idx] = (__bf16)(w - (float)h);
        }
        if (idx < 10 * 8 * 64 * 8) {          // gc1_w: GH=128 -> 8 ntiles
            int j    = idx & 7;
            int lane = (idx >> 3) & 63;
            int nt   = (idx >> 9) & 7;
            int ks   = idx >> 12;
            int k = ks * 32 + (lane >> 4) * 8 + j;
            int n = nt * 16 + (lane & 15);
            float w = gc1w[k * GH + n];
            __bf16 h = (__bf16)w;
            gwhi[idx] = h;
            gwlo[idx] = (__bf16)(w - (float)h);
        }
        if (idx < BB * NN) cnt[idx] = 0;
        if (idx < BB * PH) { Ssum[idx] = 0.f; S2sum[idx] = 0.f; }
    }
}

// ------ stage 1: 256 blocks (one clean round, 1 block/CU).
//   Each block: ng 2-row strip (dirs 0..3, symmetric-halved; 2 phases of
//   160 ch) THEN kp half-pair units u = s + 16*wave (<71).
//   FORWARD h stored only.
__global__ __launch_bounds__(512, 1) void k_edge(
    const float* __restrict__ featT, const int* __restrict__ pairs,
    const uint4* __restrict__ wglob, const float* __restrict__ b1,
    bf16* __restrict__ hstore, float* __restrict__ Ssum,
    float* __restrict__ S2sum, int E, int EKP)
{
    __shared__ ushort Wsh[40960];        // 80 KB W hi||lo
    __shared__ float RowsBuf[16000];     // 62.5 KB (ng: 96*164; kp: 48*324)
    __shared__ int kpn[48];

    int t = threadIdx.x;
    int wave = t >> 6, lane = t & 63;
    int q = lane >> 4, r = lane & 15;
    int b = blockIdx.x % BB;
    int s = blockIdx.x / BB;             // strip 0..15, source rows 2s,2s+1

    if (t < 48) kpn[t] = pairs[((size_t)b * E + t * 47) * 2];

    {   // W staging: 5120 uint4, 10 per thread
        uint4* dst = (uint4*)Wsh;
        #pragma unroll
        for (int k = 0; k < 10; ++k)
            dst[t + k * 512] = wglob[t + k * 512];
    }
    const bfrag* WH = (const bfrag*)Wsh;
    const bfrag* WL = (const bfrag*)(Wsh + 20480);

    float b1v[4];
    #pragma unroll
    for (int nt = 0; nt < 4; ++nt) b1v[nt] = b1[nt * 16 + r];
    float ps[4], ps2[4];
    #pragma unroll
    for (int nt = 0; nt < 4; ++nt) { ps[nt] = 0.f; ps2[nt] = 0.f; }

    // ---------------- ng 2-row strip, dirs 0..3 (dy<=0) ----------------
    const int dyT[4] = {-1,-1,-1, 0};
    const int dxT[4] = {-1, 0, 1,-1};
    const int pfT4[4] = {0, 961, 1953, 2914};

    int d = wave >> 1;               // direction 0..3
    int p = wave & 1;                // source row within strip
    int dy = dyT[d], dx = dxT[d];
    int y0 = dy < 0 ? 1 : 0;
    int x0 = dx < 0 ? 1 : 0;
    int ww = (dx == 0) ? 32 : 31;
    int pfF = pfT4[d];
    int y = 2 * s + p;

    // local rows staged: gy = 2s-1 + lr, lr in 0..2; source row lr = 1+p
    const float* rowI[2];
    const float* rowJ[2];
    #pragma unroll
    for (int mt = 0; mt < 2; ++mt) {
        int x  = (mt << 4) + r;
        int lr = 1 + p;
        int ni = lr * 32 + x;
        int xj = x + dx; xj = xj < 0 ? 0 : (xj > 31 ? 31 : xj);
        int nj = (lr + dy) * 32 + xj;
        rowI[mt] = &RowsBuf[ni * RSTR + q * 8];
        rowJ[mt] = &RowsBuf[nj * RSTR + q * 8];
    }

    v4f acc[2][4];
    #pragma unroll
    for (int mt = 0; mt < 2; ++mt)
        #pragma unroll
        for (int nt = 0; nt < 4; ++nt) acc[mt][nt] = (v4f)0.f;

    #pragma unroll
    for (int ph = 0; ph < 2; ++ph) {
        __syncthreads();             // prev phase reads done (also W/kpn ready)
        const int ch0 = ph * 160;
        // stage 96 nodes x 160 ch (40 float4 each)
        for (int uu = t; uu < 96 * 40; uu += 512) {
            int node = uu / 40, c4 = uu - node * 40;
            int gy = 2 * s - 1 + (node >> 5);
            if (gy >= 0) {
                int gn = gy * 32 + (node & 31);
                float4 v = *(const float4*)&featT[((size_t)b * NN + gn) * CC
                                                  + ch0 + c4 * 4];
                *(float4*)&RowsBuf[node * RSTR + c4 * 4] = v;
            }
        }
        __syncthreads();             // staging visible

        const int ksBeg = ph * 5;
        #pragma unroll
        for (int ks = ksBeg; ks < ksBeg + 5; ++ks) {
            int lc = ks * 32 - ch0;
            #pragma unroll
            for (int mt = 0; mt < 2; ++mt) {
                float4 fi0 = *(const float4*)(rowI[mt] + lc);
                float4 fi1 = *(const float4*)(rowI[mt] + lc + 4);
                float4 fj0 = *(const float4*)(rowJ[mt] + lc);
                float4 fj1 = *(const float4*)(rowJ[mt] + lc + 4);
                float df[8];
                df[0] = fabsf(fi0.x - fj0.x); df[1] = fabsf(fi0.y - fj0.y);
                df[2] = fabsf(fi0.z - fj0.z); df[3] = fabsf(fi0.w - fj0.w);
                df[4] = fabsf(fi1.x - fj1.x); df[5] = fabsf(fi1.y - fj1.y);
                df[6] = fabsf(fi1.z - fj1.z); df[7] = fabsf(fi1.w - fj1.w);

                bfrag ah, al;
                #pragma unroll
                for (int kk = 0; kk < 8; ++kk) {
                    __bf16 h = (__bf16)df[kk];
                    ah[kk] = h;
                    al[kk] = (__bf16)(df[kk] - (float)h);
                }
                #pragma unroll
                for (int nt = 0; nt < 4; ++nt) {
                    bfrag bh = WH[((ks * 4 + nt) << 6) + lane];
                    bfrag bl = WL[((ks * 4 + nt) << 6) + lane];
                    acc[mt][nt] = __builtin_amdgcn_mfma_f32_16x16x32_bf16(
                        ah, bh, acc[mt][nt], 0, 0, 0);
                    acc[mt][nt] = __builtin_amdgcn_mfma_f32_16x16x32_bf16(
                        ah, bl, acc[mt][nt], 0, 0, 0);
                    acc[mt][nt] = __builtin_amdgcn_mfma_f32_16x16x32_bf16(
                        al, bh, acc[mt][nt], 0, 0, 0);
                }
            }
        }
    }

    // -------- kp staging issued FIRST (overlaps the ng h-store below) -----
    __syncthreads();     // all ng RowsBuf reads done
    {   // kp row staging: 48 rows x 80 float4
        const float4* src = (const float4*)featT;
        #pragma unroll
        for (int k = 0; k < 8; ++k) {
            int idx = t + k * 512;
            if (idx < 48 * 80) {
                int slot = idx / 80, c4 = idx - slot * 80;
                float4 v = src[((size_t)b * NN + kpn[slot]) * 80 + c4];
                *(float4*)&RowsBuf[slot * ROWP + c4 * 4] = v;
            }
        }
    }

    // ng store (FORWARD only) + BN stats (register/global only; overlaps
    // the kp staging above — no LDS dependence)
    #pragma unroll
    for (int mt = 0; mt < 2; ++mt) {
        #pragma unroll
        for (int reg = 0; reg < 4; ++reg) {
            int xi = (mt << 4) + q * 4 + reg;
            int y2 = y + dy, x2 = xi + dx;
            bool valid = ((unsigned)y2 < 32u) && ((unsigned)x2 < 32u);
            if (valid) {
                int e1 = EKP + pfF + (y - y0) * ww + (xi - x0);
                bf16* h1 = hstore + ((size_t)b * E + e1) * PH + r;
                #pragma unroll
                for (int nt = 0; nt < 4; ++nt) {
                    float v = acc[mt][nt][reg] + b1v[nt];
                    h1[nt * 16] = __float2bfloat16(v);
                    ps[nt] += v;
                    ps2[nt] = fmaf(v, v, ps2[nt]);
                }
            }
        }
    }

    __syncthreads();     // kp rows visible

    int u = s + 16 * wave;               // kp unit id within image, 0..127
    if (u < 71) {
        int mA = u * 16 + r;
        if (mA >= NKPH) mA = NKPH - 1;
        int aI, yI;
        tri_decode(mA, aI, yI);
        const float* rI = &RowsBuf[aI * ROWP + q * 8];
        const float* rJ = &RowsBuf[yI * ROWP + q * 8];

        v4f acc2[4];
        #pragma unroll
        for (int nt = 0; nt < 4; ++nt) acc2[nt] = (v4f)0.f;

        #pragma unroll
        for (int ks = 0; ks < 10; ++ks) {
            float4 fi0 = *(const float4*)(rI + ks * 32);
            float4 fi1 = *(const float4*)(rI + ks * 32 + 4);
            float4 fj0 = *(const float4*)(rJ + ks * 32);
            float4 fj1 = *(const float4*)(rJ + ks * 32 + 4);
            float df[8];
            df[0] = fabsf(fi0.x - fj0.x); df[1] = fabsf(fi0.y - fj0.y);
            df[2] = fabsf(fi0.z - fj0.z); df[3] = fabsf(fi0.w - fj0.w);
            df[4] = fabsf(fi1.x - fj1.x); df[5] = fabsf(fi1.y - fj1.y);
            df[6] = fabsf(fi1.z - fj1.z); df[7] = fabsf(fi1.w - fj1.w);

            bfrag ah, al;
            #pragma unroll
            for (int kk = 0; kk < 8; ++kk) {
                __bf16 h = (__bf16)df[kk];
                ah[kk] = h;
                al[kk] = (__bf16)(df[kk] - (float)h);
            }
            #pragma unroll
            for (int nt = 0; nt < 4; ++nt) {
                bfrag bh = WH[((ks * 4 + nt) << 6) + lane];
                bfrag bl = WL[((ks * 4 + nt) << 6) + lane];
                acc2[nt] = __builtin_amdgcn_mfma_f32_16x16x32_bf16(ah, bh, acc2[nt], 0, 0, 0);
                acc2[nt] = __builtin_amdgcn_mfma_f32_16x16x32_bf16(ah, bl, acc2[nt], 0, 0, 0);
                acc2[nt] = __builtin_amdgcn_mfma_f32_16x16x32_bf16(al, bh, acc2[nt], 0, 0, 0);
            }
        }

        #pragma unroll
        for (int reg = 0; reg < 4; ++reg) {
            int mC = u * 16 + q * 4 + reg;
            if (mC < NKPH) {
                int a, yk;
                tri_decode(mC, a, yk);
                int e1 = a * 47 + yk - 1;    // forward (a,yk), a<yk
                bf16* h1 = hstore + ((size_t)b * E + e1) * PH + r;
                #pragma unroll
                for (int nt = 0; nt < 4; ++nt) {
                    float v = acc2[nt][reg] + b1v[nt];
                    h1[nt * 16] = __float2bfloat16(v);
                    ps[nt] += v;
                    ps2[nt] = fmaf(v, v, ps2[nt]);
                }
            }
        }
    }

    // common BN reduce: cross-lane q-sum, few LDS atomics; x2 for symmetric
    // duplicate edges.
    __syncthreads();
    float* sS  = RowsBuf;
    float* sS2 = RowsBuf + PH;
    if (t < PH) { sS[t] = 0.f; sS2[t] = 0.f; }
    __syncthreads();
    #pragma unroll
    for (int nt = 0; nt < 4; ++nt) {
        float p1 = ps[nt]  + __shfl_xor(ps[nt], 16, 64);
        p1 += __shfl_xor(p1, 32, 64);
        float p2 = ps2[nt] + __shfl_xor(ps2[nt], 16, 64);
        p2 += __shfl_xor(p2, 32, 64);
        if (lane < 16) {
            atomicAdd(&sS[nt * 16 + r],  2.0f * p1);
            atomicAdd(&sS2[nt * 16 + r], 2.0f * p2);
        }
    }
    __syncthreads();
    if (t < PH) {
        atomicAdd(&Ssum[b * PH + t],  sS[t]);
        atomicAdd(&S2sum[b * PH + t], sS2[t]);
    }
}

// -- merged: gc1 (blocks [0,512)) + BN-final/edge-val over UNDIRECTED edges
//    (blocks [512, 512+16*20)): one h read + sigmoid per undirected edge,
//    scatter BOTH ELL directions.  g1 stored as FP16 (halves spmm1 gather).
__global__ __launch_bounds__(256, 2) void k_val_gc1(
    const float* __restrict__ featT, const __bf16* __restrict__ gwhi,
    const __bf16* __restrict__ gwlo, __half* __restrict__ g1,
    const bf16* __restrict__ hstore, const float* __restrict__ Ssum,
    const float* __restrict__ S2sum, const float* __restrict__ gamma,
    const float* __restrict__ beta, const float* __restrict__ w2,
    const float* __restrict__ b2, const int* __restrict__ pairs,
    int* __restrict__ cnt, int* __restrict__ ecol, float* __restrict__ eval_,
    int E, int EKP, int nGC)
{
    __shared__ ushort WG[40960];   // 80 KB (gc1); edge_val reuses <1 KB of it

    int t = threadIdx.x;
    if ((int)blockIdx.x < nGC) {
        // -------------------- gc1 branch --------------------
        int b = blockIdx.x % BB;
        int rem = blockIdx.x / BB;     // 0..31
        int half = rem & 1;
        int m0 = b * NN + (rem >> 1) * 64;

        {
            uint4* dst = (uint4*)WG;
            const uint4* sh = (const uint4*)gwhi;
            const uint4* sl = (const uint4*)gwlo;
            #pragma unroll
            for (int k = 0; k < 10; ++k) {
                int u = t + k * 256;
                int chunk = u >> 6, v = u & 63;
                int ks = chunk >> 2, ntp = chunk & 3;
                int src = (ks * 8 + half * 4 + ntp) * 64 + v;
                dst[u]        = sh[src];
                dst[2560 + u] = sl[src];
            }
        }

        int wave = t >> 6, lane = t & 63;
        int q = lane >> 4, r = lane & 15;
        const float* fp = featT + (size_t)(m0 + wave * 16 + r) * CC + q * 8;

        float fa[2][8];
        auto LOADA = [&](int ks, int buf) {
            const float4* p = (const float4*)(fp + ks * 32);
            *(float4*)&fa[buf][0] = p[0];
            *(float4*)&fa[buf][4] = p[1];
        };

        v4f acc[4];
        #pragma unroll
        for (int nt = 0; nt < 4; ++nt) acc[nt] = (v4f)0.f;

        LOADA(0, 0);
        __syncthreads();

        const bfrag* WGH = (const bfrag*)WG;
        const bfrag* WGL = (const bfrag*)(WG + 20480);

        #pragma unroll
        for (int ks = 0; ks < 10; ++ks) {
            int cur = ks & 1;
            if (ks < 9) LOADA(ks + 1, cur ^ 1);
            bfrag ah, al;
            #pragma unroll
            for (int kk = 0; kk < 8; ++kk) {
                float d = fa[cur][kk];
                __bf16 h = (__bf16)d;
                ah[kk] = h;
                al[kk] = (__bf16)(d - (float)h);
            }
            #pragma unroll
            for (int nt = 0; nt < 4; ++nt) {
                bfrag bh = WGH[((ks * 4 + nt) << 6) + lane];
                bfrag bl = WGL[((ks * 4 + nt) << 6) + lane];
                acc[nt] = __builtin_amdgcn_mfma_f32_16x16x32_bf16(ah, bh, acc[nt], 0, 0, 0);
                acc[nt] = __builtin_amdgcn_mfma_f32_16x16x32_bf16(ah, bl, acc[nt], 0, 0, 0);
                acc[nt] = __builtin_amdgcn_mfma_f32_16x16x32_bf16(al, bh, acc[nt], 0, 0, 0);
            }
        }
        #pragma unroll
        for (int nt = 0; nt < 4; ++nt) {
            #pragma unroll
            for (int reg = 0; reg < 4; ++reg) {
                int m = m0 + wave * 16 + q * 4 + reg;
                g1[(size_t)m * GH + (half * 4 + nt) * 16 + r] =
                    __float2half(acc[nt][reg]);
            }
        }
    } else {
        // ---------- edge_val branch: undirected edges, dual scatter --------
        float* ca = (float*)WG;
        float* cb = ca + PH;
        int* kpl = (int*)(cb + PH);
        int blk = blockIdx.x - nGC;
        int b = blk % BB;
        int u = (blk / BB) * 256 + t;
        if (t < PH) {
            int l = t;
            float mu = Ssum[b * PH + l] / E;
            float var = S2sum[b * PH + l] / E - mu * mu;
            float A = rsqrtf(var + 1e-5f) * gamma[l];
            ca[l] = A;
            cb[l] = beta[l] - mu * A;
        }
        if (t < 48) kpl[t] = pairs[((size_t)b * E + t * 47) * 2];
        __syncthreads();
        if (u >= NUD) return;

        int i, j, hrow;
        if (u < NKPH) {
            int a, yk;
            tri_decode(u, a, yk);
            i = kpl[a]; j = kpl[yk];
            hrow = a * 47 + yk - 1;
        } else {
            int up = u - NKPH;           // [0, 3906) forward-region offset
            int pf, ww, y0, x0, dy, dx;
            if (up < 961)       { pf = 0;    ww = 31; y0 = 1; x0 = 1; dy = -1; dx = -1; }
            else if (up < 1953) { pf = 961;  ww = 32; y0 = 1; x0 = 0; dy = -1; dx = 0;  }
            else if (up < 2914) { pf = 1953; ww = 31; y0 = 1; x0 = 0; dy = -1; dx = 1;  }
            else                { pf = 2914; ww = 31; y0 = 0; x0 = 1; dy = 0;  dx = -1; }
            int rel = up - pf;
            int yR = rel / ww, xC = rel - yR * ww;
            int yy = yR + y0, xi = xC + x0;
            i = yy * 32 + xi;
            j = (yy + dy) * 32 + (xi + dx);
            hrow = EKP + up;             // undirected ng id == forward hstore offset
        }

        const bfrag* hp = (const bfrag*)(hstore + ((size_t)b * E + hrow) * PH);
        float acc = 0.f;
        #pragma unroll
        for (int l8 = 0; l8 < 8; ++l8) {
            bfrag hv = hp[l8];
            #pragma unroll
            for (int c = 0; c < 8; ++c) {
                int l = l8 * 8 + c;
                float x = fmaf((float)hv[c], ca[l], cb[l]);
                x = x > 0.f ? x : 0.f;
                acc = fmaf(x, w2[l], acc);
            }
        }
        float edge = 1.f / (1.f + __expf(-(acc + b2[0])));
        int ri = b * NN + i;
        int rj = b * NN + j;
        int s1 = atomicAdd(&cnt[ri], 1);
        if (s1 < ELLW) {
            ecol[ri * ELLW + s1]  = j;
            eval_[ri * ELLW + s1] = edge;
        }
        int s2 = atomicAdd(&cnt[rj], 1);
        if (s2 < ELLW) {
            ecol[rj * ELLW + s2]  = i;
            eval_[rj * ELLW + s2] = edge;
        }
    }
}

// ------- stage 5: g2 = (leaky(adj@g1)) @ gc2_w  (4 nodes/block, f16 g1) --
__global__ __launch_bounds__(256) void k_spmm1(
    const __half* __restrict__ g1, const int* __restrict__ cnt,
    const int* __restrict__ ecol, const float* __restrict__ eval_,
    const float* __restrict__ w2g, float* __restrict__ g2)
{
    int tid = threadIdx.x & 63;
    int node = blockIdx.x * 4 + (threadIdx.x >> 6);
    int base = node & ~(NN - 1);
    float wa = w2g[2 * tid], wb = w2g[2 * tid + 1];
    int c = cnt[node];
    const int* ec = ecol + (size_t)node * ELLW;
    const float* ev = eval_ + (size_t)node * ELLW;
    const __half2* g1v = (const __half2*)g1;
    float aa = 0.f, ab = 0.f;
    int s = 0;
    for (; s + 4 <= c; s += 4) {
        int j0 = ec[s], j1 = ec[s + 1], j2 = ec[s + 2], j3 = ec[s + 3];
        float v0 = ev[s], v1 = ev[s + 1], v2 = ev[s + 2], v3 = ev[s + 3];
        __half2 u0 = g1v[((size_t)(base + j0)) * 64 + tid];
        __half2 u1 = g1v[((size_t)(base + j1)) * 64 + tid];
        __half2 u2 = g1v[((size_t)(base + j2)) * 64 + tid];
        __half2 u3 = g1v[((size_t)(base + j3)) * 64 + tid];
        aa = fmaf(v0, __low2float(u0), aa); ab = fmaf(v0, __high2float(u0), ab);
        aa = fmaf(v1, __low2float(u1), aa); ab = fmaf(v1, __high2float(u1), ab);
        aa = fmaf(v2, __low2float(u2), aa); ab = fmaf(v2, __high2float(u2), ab);
        aa = fmaf(v3, __low2float(u3), aa); ab = fmaf(v3, __high2float(u3), ab);
    }
    for (; s < c; ++s) {
        __half2 u = g1v[((size_t)(base + ec[s])) * 64 + tid];
        float v = ev[s];
        aa = fmaf(v, __low2float(u), aa); ab = fmaf(v, __high2float(u), ab);
    }
    float h1a = aa > 0.f ? aa : 0.2f * aa;
    float h1b = ab > 0.f ? ab : 0.2f * ab;
    float p = h1a * wa + h1b * wb;
    #pragma unroll
    for (int off = 32; off >= 1; off >>= 1) p += __shfl_down(p, off, 64);
    if (tid == 0) g2[node] = p;
}

// ------------- stage 6: out = sigmoid(adj @ g2) (4 nodes/block) ----------
__global__ __launch_bounds__(256) void k_spmm2(
    const float* __restrict__ g2, const int* __restrict__ cnt,
    const int* __restrict__ ecol, const float* __restrict__ eval_,
    float* __restrict__ out)
{
    int lane = threadIdx.x & 63;
    int node = blockIdx.x * 4 + (threadIdx.x >> 6);
    int base = node & ~(NN - 1);
    int c = cnt[node];
    float p = 0.f;
    if (lane < c) {
        int j = ecol[(size_t)node * ELLW + lane];
        p = eval_[(size_t)node * ELLW + lane] * g2[base + j];
    }
    #pragma unroll
    for (int off = 32; off >= 1; off >>= 1) p += __shfl_down(p, off, 64);
    if (lane == 0) out[node] = 1.f / (1.f + __expf(-p));
}

extern "C" void kernel_launch(void* const* d_in, const int* in_sizes, int n_in,
                              void* d_out, int out_size, void* d_ws, size_t ws_size,
                              hipStream_t stream)
{
    const float* search = (const float*)d_in[0];
    const float* xcorr  = (const float*)d_in[1];
    const int*   pairs  = (const int*)d_in[2];
    const float* w1     = (const float*)d_in[3];
    const float* b1     = (const float*)d_in[4];
    const float* gamma  = (const float*)d_in[5];
    const float* beta   = (const float*)d_in[6];
    const float* w2     = (const float*)d_in[7];
    const float* b2     = (const float*)d_in[8];
    const float* gc1w   = (const float*)d_in[9];
    const float* gc2w   = (const float*)d_in[10];
    float* out = (float*)d_out;

    int E   = in_sizes[2] / (BB * 2);    // 10068
    int EKP = E - NENG;                  // 2256 keypoint-clique edges
    int nbU  = (NUD + 255) / 256;        // 20 undirected-edge tiles
    int nGC  = BB * 32;                  // 512 gc1 blocks

    char* ws = (char*)d_ws;
    size_t off = 0;
    auto alloc = [&](size_t bytes) {
        size_t o = off;
        off += (bytes + 255) & ~(size_t)255;
        return o;
    };
    __bf16* whi   = (__bf16*)(ws + alloc(10 * 4 * 64 * 8 * 2));   // 40960 B
    __bf16* wlo   = (__bf16*)(ws + alloc(10 * 4 * 64 * 8 * 2));   // contiguous after whi
    __bf16* gwhi  = (__bf16*)(ws + alloc(10 * 8 * 64 * 8 * 2));
    __bf16* gwlo  = (__bf16*)(ws + alloc(10 * 8 * 64 * 8 * 2));
    float* featT  = (float*)(ws + alloc((size_t)BB * NN * CC * 4));
    bf16*  hstore = (bf16*)(ws + alloc((size_t)BB * E * PH * 2));
    float* Ssum   = (float*)(ws + alloc(BB * PH * 4));
    float* S2sum  = (float*)(ws + alloc(BB * PH * 4));
    int*   cnt    = (int*)(ws + alloc(BB * NN * 4));
    int*   ecol   = (int*)(ws + alloc((size_t)BB * NN * ELLW * 4));
    float* eval_  = (float*)(ws + alloc((size_t)BB * NN * ELLW * 4));
    __half* g1    = (__half*)(ws + alloc((size_t)BB * NN * GH * 2));
    float* g2     = (float*)(ws + alloc(BB * NN * 4));
    (void)ws_size; (void)n_in; (void)out_size;

    k_prep_transpose<<<dim3(BB * 320 + 160), dim3(256), 0, stream>>>(
        search, xcorr, featT, w1, gc1w, whi, wlo, gwhi, gwlo, cnt, Ssum, S2sum);
    k_edge<<<dim3(BB * 16), dim3(512), 0, stream>>>(featT, pairs,
                                                    (const uint4*)whi, b1,
                                                    hstore, Ssum, S2sum,
                                                    E, EKP);
    k_val_gc1<<<dim3(nGC + BB * nbU), dim3(256), 0, stream>>>(
        featT, gwhi, gwlo, g1, hstore, Ssum, S2sum, gamma, beta, w2, b2,
        pairs, cnt, ecol, eval_, E, EKP, nGC);
    k_spmm1<<<dim3(BB * NN / 4), dim3(256), 0, stream>>>(g1, cnt, ecol, eval_,
                                                         gc2w, g2);
    k_spmm2<<<dim3(BB * NN / 4), dim3(256), 0, stream>>>(g2, cnt, ecol, eval_, out);
}

// Round 12
// 148.042 us; speedup vs baseline: 1.1623x; 1.0137x over previous
//
#include <hip/hip_runtime.h>
#include <hip/hip_bf16.h>
#include <hip/hip_fp16.h>

#define BB 16
#define NN 1024
#define CS 256
#define CX 64
#define CC 320
#define PH 64
#define GH 128
#define ELLW 64
#define NENG 7812   // 8-neigh edges per image (H=W=32)
#define ROWP 324    // padded kp row stride in floats (320 + 4)
#define RSTR 164    // ng LDS row stride in floats (160 + 4); (4r+8q)%32 -> 2-way only
#define NKPH 1128   // kp half-pairs (a<y)
#define NGU  3906   // undirected ng edges (forward dirs 0..3)
#define NUD  5034   // total undirected edges per image (NKPH + NGU)

typedef __hip_bfloat16 bf16;
typedef __attribute__((ext_vector_type(8))) __bf16 bfrag;   // 8 bf16 = 4 VGPRs
typedef __attribute__((ext_vector_type(4))) float v4f;

// triangular decode: m in [0,1128) -> pair (a,y), a<y, kp slots 0..47
__device__ __forceinline__ void tri_decode(int m, int& a, int& y) {
    float s = sqrtf((float)(9025 - 8 * m));
    int aa = (int)((95.0f - s) * 0.5f);
    if (aa > 0 && 47 * aa - (aa * (aa - 1)) / 2 > m) --aa;
    while (47 * (aa + 1) - ((aa + 1) * aa) / 2 <= m) ++aa;
    a = aa;
    y = aa + 1 + (m - (47 * aa - (aa * (aa - 1)) / 2));
}

// ---- merged prep (W packing, zero-init) + transpose [B,C,N]->[B,N,C] ----
// blocks [0, 5120): transpose; blocks [5120, 5280): prep.
__global__ __launch_bounds__(256) void k_prep_transpose(
    const float* __restrict__ search, const float* __restrict__ xcorr,
    float* __restrict__ featT,
    const float* __restrict__ w1, const float* __restrict__ gc1w,
    __bf16* __restrict__ whi, __bf16* __restrict__ wlo,
    __bf16* __restrict__ gwhi, __bf16* __restrict__ gwlo,
    int* __restrict__ cnt, float* __restrict__ Ssum, float* __restrict__ S2sum)
{
    __shared__ float tile[32][33];
    int blk = blockIdx.x;
    int tid = threadIdx.x;
    if (blk < BB * 320) {
        // ---------------- transpose branch ----------------
        int b   = blk % BB;
        int rem = blk / BB;       // 0..319
        int ct  = rem >> 5;       // 10 channel tiles
        int ntl = rem & 31;       // 32 node tiles
        int cl = tid >> 5, nl = tid & 31;
        const float* sb = search + (size_t)b * CS * NN;
        const float* xb = xcorr + (size_t)b * CX * NN;
        #pragma unroll
        for (int f = 0; f < 4; ++f) {
            int c = ct * 32 + cl + f * 8;
            int n = ntl * 32 + nl;
            float v = (c < CS) ? sb[(size_t)c * NN + n] : xb[(size_t)(c - CS) * NN + n];
            tile[cl + f * 8][nl] = v;
        }
        __syncthreads();
        #pragma unroll
        for (int f = 0; f < 4; ++f) {
            int nr = cl + f * 8;
            int cc = nl;
            featT[((size_t)b * NN + ntl * 32 + nr) * CC + ct * 32 + cc] = tile[cc][nr];
        }
    } else {
        // ---------------- prep branch ----------------
        int idx = (blk - BB * 320) * 256 + tid;
        if (idx < 10 * 4 * 64 * 8) {          // W1: PH=64 -> 4 ntiles
            int j    = idx & 7;
            int lane = (idx >> 3) & 63;
            int nt   = (idx >> 9) & 3;
            int ks   = idx >> 11;
            int k = ks * 32 + (lane >> 4) * 8 + j;
            int n = nt * 16 + (lane & 15);
            float w = w1[k * PH + n];
            __bf16 h = (__bf16)w;
            whi[idx] = h;
            wlo[idx] = (__bf16)(w - (float)h);
        }
        if (idx < 10 * 8 * 64 * 8) {          // gc1_w: GH=128 -> 8 ntiles
            int j    = idx & 7;
            int lane = (idx >> 3) & 63;
            int nt   = (idx >> 9) & 7;
            int ks   = idx >> 12;
            int k = ks * 32 + (lane >> 4) * 8 + j;
            int n = nt * 16 + (lane & 15);
            float w = gc1w[k * GH + n];
            __bf16 h = (__bf16)w;
            gwhi[idx] = h;
            gwlo[idx] = (__bf16)(w - (float)h);
        }
        if (idx < BB * NN) cnt[idx] = 0;
        if (idx < BB * PH) { Ssum[idx] = 0.f; S2sum[idx] = 0.f; }
    }
}

// ------ stage 1: 256 blocks (one clean round, 1 block/CU).
//   Each block: ng 2-row strip (dirs 0..3, symmetric-halved; 2 phases of
//   160 ch) THEN kp half-pair units u = s + 16*wave (<71).
//   FORWARD h stored only.
__global__ __launch_bounds__(512, 1) void k_edge(
    const float* __restrict__ featT, const int* __restrict__ pairs,
    const uint4* __restrict__ wglob, const float* __restrict__ b1,
    bf16* __restrict__ hstore, float* __restrict__ Ssum,
    float* __restrict__ S2sum, int E, int EKP)
{
    __shared__ ushort Wsh[40960];        // 80 KB W hi||lo
    __shared__ float RowsBuf[16000];     // 62.5 KB (ng: 96*164; kp: 48*324)
    __shared__ int kpn[48];

    int t = threadIdx.x;
    int wave = t >> 6, lane = t & 63;
    int q = lane >> 4, r = lane & 15;
    int b = blockIdx.x % BB;
    int s = blockIdx.x / BB;             // strip 0..15, source rows 2s,2s+1

    if (t < 48) kpn[t] = pairs[((size_t)b * E + t * 47) * 2];

    {   // W staging: 5120 uint4, 10 per thread
        uint4* dst = (uint4*)Wsh;
        #pragma unroll
        for (int k = 0; k < 10; ++k)
            dst[t + k * 512] = wglob[t + k * 512];
    }
    const bfrag* WH = (const bfrag*)Wsh;
    const bfrag* WL = (const bfrag*)(Wsh + 20480);

    float b1v[4];
    #pragma unroll
    for (int nt = 0; nt < 4; ++nt) b1v[nt] = b1[nt * 16 + r];
    float ps[4], ps2[4];
    #pragma unroll
    for (int nt = 0; nt < 4; ++nt) { ps[nt] = 0.f; ps2[nt] = 0.f; }

    // ---------------- ng 2-row strip, dirs 0..3 (dy<=0) ----------------
    const int dyT[4] = {-1,-1,-1, 0};
    const int dxT[4] = {-1, 0, 1,-1};
    const int pfT4[4] = {0, 961, 1953, 2914};

    int d = wave >> 1;               // direction 0..3
    int p = wave & 1;                // source row within strip
    int dy = dyT[d], dx = dxT[d];
    int y0 = dy < 0 ? 1 : 0;
    int x0 = dx < 0 ? 1 : 0;
    int ww = (dx == 0) ? 32 : 31;
    int pfF = pfT4[d];
    int y = 2 * s + p;

    // local rows staged: gy = 2s-1 + lr, lr in 0..2; source row lr = 1+p
    const float* rowI[2];
    const float* rowJ[2];
    #pragma unroll
    for (int mt = 0; mt < 2; ++mt) {
        int x  = (mt << 4) + r;
        int lr = 1 + p;
        int ni = lr * 32 + x;
        int xj = x + dx; xj = xj < 0 ? 0 : (xj > 31 ? 31 : xj);
        int nj = (lr + dy) * 32 + xj;
        rowI[mt] = &RowsBuf[ni * RSTR + q * 8];
        rowJ[mt] = &RowsBuf[nj * RSTR + q * 8];
    }

    v4f acc[2][4];
    #pragma unroll
    for (int mt = 0; mt < 2; ++mt)
        #pragma unroll
        for (int nt = 0; nt < 4; ++nt) acc[mt][nt] = (v4f)0.f;

    #pragma unroll
    for (int ph = 0; ph < 2; ++ph) {
        __syncthreads();             // prev phase reads done (also W/kpn ready)
        const int ch0 = ph * 160;
        // stage 96 nodes x 160 ch (40 float4 each)
        for (int uu = t; uu < 96 * 40; uu += 512) {
            int node = uu / 40, c4 = uu - node * 40;
            int gy = 2 * s - 1 + (node >> 5);
            if (gy >= 0) {
                int gn = gy * 32 + (node & 31);
                float4 v = *(const float4*)&featT[((size_t)b * NN + gn) * CC
                                                  + ch0 + c4 * 4];
                *(float4*)&RowsBuf[node * RSTR + c4 * 4] = v;
            }
        }
        __syncthreads();             // staging visible

        const int ksBeg = ph * 5;
        #pragma unroll
        for (int ks = ksBeg; ks < ksBeg + 5; ++ks) {
            int lc = ks * 32 - ch0;
            #pragma unroll
            for (int mt = 0; mt < 2; ++mt) {
                float4 fi0 = *(const float4*)(rowI[mt] + lc);
                float4 fi1 = *(const float4*)(rowI[mt] + lc + 4);
                float4 fj0 = *(const float4*)(rowJ[mt] + lc);
                float4 fj1 = *(const float4*)(rowJ[mt] + lc + 4);
                float df[8];
                df[0] = fabsf(fi0.x - fj0.x); df[1] = fabsf(fi0.y - fj0.y);
                df[2] = fabsf(fi0.z - fj0.z); df[3] = fabsf(fi0.w - fj0.w);
                df[4] = fabsf(fi1.x - fj1.x); df[5] = fabsf(fi1.y - fj1.y);
                df[6] = fabsf(fi1.z - fj1.z); df[7] = fabsf(fi1.w - fj1.w);

                bfrag ah, al;
                #pragma unroll
                for (int kk = 0; kk < 8; ++kk) {
                    __bf16 h = (__bf16)df[kk];
                    ah[kk] = h;
                    al[kk] = (__bf16)(df[kk] - (float)h);
                }
                #pragma unroll
                for (int nt = 0; nt < 4; ++nt) {
                    bfrag bh = WH[((ks * 4 + nt) << 6) + lane];
                    bfrag bl = WL[((ks * 4 + nt) << 6) + lane];
                    acc[mt][nt] = __builtin_amdgcn_mfma_f32_16x16x32_bf16(
                        ah, bh, acc[mt][nt], 0, 0, 0);
                    acc[mt][nt] = __builtin_amdgcn_mfma_f32_16x16x32_bf16(
                        ah, bl, acc[mt][nt], 0, 0, 0);
                    acc[mt][nt] = __builtin_amdgcn_mfma_f32_16x16x32_bf16(
                        al, bh, acc[mt][nt], 0, 0, 0);
                }
            }
        }
    }

    // -------- kp staging issued FIRST (overlaps the ng h-store below) -----
    __syncthreads();     // all ng RowsBuf reads done
    {   // kp row staging: 48 rows x 80 float4
        const float4* src = (const float4*)featT;
        #pragma unroll
        for (int k = 0; k < 8; ++k) {
            int idx = t + k * 512;
            if (idx < 48 * 80) {
                int slot = idx / 80, c4 = idx - slot * 80;
                float4 v = src[((size_t)b * NN + kpn[slot]) * 80 + c4];
                *(float4*)&RowsBuf[slot * ROWP + c4 * 4] = v;
            }
        }
    }

    // ng store (FORWARD only) + BN stats (register/global only; overlaps
    // the kp staging above — no LDS dependence)
    #pragma unroll
    for (int mt = 0; mt < 2; ++mt) {
        #pragma unroll
        for (int reg = 0; reg < 4; ++reg) {
            int xi = (mt << 4) + q * 4 + reg;
            int y2 = y + dy, x2 = xi + dx;
            bool valid = ((unsigned)y2 < 32u) && ((unsigned)x2 < 32u);
            if (valid) {
                int e1 = EKP + pfF + (y - y0) * ww + (xi - x0);
                bf16* h1 = hstore + ((size_t)b * E + e1) * PH + r;
                #pragma unroll
                for (int nt = 0; nt < 4; ++nt) {
                    float v = acc[mt][nt][reg] + b1v[nt];
                    h1[nt * 16] = __float2bfloat16(v);
                    ps[nt] += v;
                    ps2[nt] = fmaf(v, v, ps2[nt]);
                }
            }
        }
    }

    __syncthreads();     // kp rows visible

    int u = s + 16 * wave;               // kp unit id within image, 0..127
    if (u < 71) {
        int mA = u * 16 + r;
        if (mA >= NKPH) mA = NKPH - 1;
        int aI, yI;
        tri_decode(mA, aI, yI);
        const float* rI = &RowsBuf[aI * ROWP + q * 8];
        const float* rJ = &RowsBuf[yI * ROWP + q * 8];

        v4f acc2[4];
        #pragma unroll
        for (int nt = 0; nt < 4; ++nt) acc2[nt] = (v4f)0.f;

        #pragma unroll
        for (int ks = 0; ks < 10; ++ks) {
            float4 fi0 = *(const float4*)(rI + ks * 32);
            float4 fi1 = *(const float4*)(rI + ks * 32 + 4);
            float4 fj0 = *(const float4*)(rJ + ks * 32);
            float4 fj1 = *(const float4*)(rJ + ks * 32 + 4);
            float df[8];
            df[0] = fabsf(fi0.x - fj0.x); df[1] = fabsf(fi0.y - fj0.y);
            df[2] = fabsf(fi0.z - fj0.z); df[3] = fabsf(fi0.w - fj0.w);
            df[4] = fabsf(fi1.x - fj1.x); df[5] = fabsf(fi1.y - fj1.y);
            df[6] = fabsf(fi1.z - fj1.z); df[7] = fabsf(fi1.w - fj1.w);

            bfrag ah, al;
            #pragma unroll
            for (int kk = 0; kk < 8; ++kk) {
                __bf16 h = (__bf16)df[kk];
                ah[kk] = h;
                al[kk] = (__bf16)(df[kk] - (float)h);
            }
            #pragma unroll
            for (int nt = 0; nt < 4; ++nt) {
                bfrag bh = WH[((ks * 4 + nt) << 6) + lane];
                bfrag bl = WL[((ks * 4 + nt) << 6) + lane];
                acc2[nt] = __builtin_amdgcn_mfma_f32_16x16x32_bf16(ah, bh, acc2[nt], 0, 0, 0);
                acc2[nt] = __builtin_amdgcn_mfma_f32_16x16x32_bf16(ah, bl, acc2[nt], 0, 0, 0);
                acc2[nt] = __builtin_amdgcn_mfma_f32_16x16x32_bf16(al, bh, acc2[nt], 0, 0, 0);
            }
        }

        #pragma unroll
        for (int reg = 0; reg < 4; ++reg) {
            int mC = u * 16 + q * 4 + reg;
            if (mC < NKPH) {
                int a, yk;
                tri_decode(mC, a, yk);
                int e1 = a * 47 + yk - 1;    // forward (a,yk), a<yk
                bf16* h1 = hstore + ((size_t)b * E + e1) * PH + r;
                #pragma unroll
                for (int nt = 0; nt < 4; ++nt) {
                    float v = acc2[nt][reg] + b1v[nt];
                    h1[nt * 16] = __float2bfloat16(v);
                    ps[nt] += v;
                    ps2[nt] = fmaf(v, v, ps2[nt]);
                }
            }
        }
    }

    // common BN reduce: cross-lane q-sum, few LDS atomics; x2 for symmetric
    // duplicate edges.
    __syncthreads();
    float* sS  = RowsBuf;
    float* sS2 = RowsBuf + PH;
    if (t < PH) { sS[t] = 0.f; sS2[t] = 0.f; }
    __syncthreads();
    #pragma unroll
    for (int nt = 0; nt < 4; ++nt) {
        float p1 = ps[nt]  + __shfl_xor(ps[nt], 16, 64);
        p1 += __shfl_xor(p1, 32, 64);
        float p2 = ps2[nt] + __shfl_xor(ps2[nt], 16, 64);
        p2 += __shfl_xor(p2, 32, 64);
        if (lane < 16) {
            atomicAdd(&sS[nt * 16 + r],  2.0f * p1);
            atomicAdd(&sS2[nt * 16 + r], 2.0f * p2);
        }
    }
    __syncthreads();
    if (t < PH) {
        atomicAdd(&Ssum[b * PH + t],  sS[t]);
        atomicAdd(&S2sum[b * PH + t], sS2[t]);
    }
}

// -- merged: gc1 (blocks [0,512)) + BN-final/edge-val over UNDIRECTED edges
//    (blocks [512, 512+16*20)): one h read + sigmoid per undirected edge,
//    scatter BOTH ELL directions.  g1 stored as FP16 (halves spmm1 gather).
__global__ __launch_bounds__(256, 2) void k_val_gc1(
    const float* __restrict__ featT, const __bf16* __restrict__ gwhi,
    const __bf16* __restrict__ gwlo, __half* __restrict__ g1,
    const bf16* __restrict__ hstore, const float* __restrict__ Ssum,
    const float* __restrict__ S2sum, const float* __restrict__ gamma,
    const float* __restrict__ beta, const float* __restrict__ w2,
    const float* __restrict__ b2, const int* __restrict__ pairs,
    int* __restrict__ cnt, int* __restrict__ ecol, float* __restrict__ eval_,
    int E, int EKP, int nGC)
{
    __shared__ ushort WG[40960];   // 80 KB (gc1); edge_val reuses <1 KB of it

    int t = threadIdx.x;
    if ((int)blockIdx.x < nGC) {
        // -------------------- gc1 branch --------------------
        int b = blockIdx.x % BB;
        int rem = blockIdx.x / BB;     // 0..31
        int half = rem & 1;
        int m0 = b * NN + (rem >> 1) * 64;

        {
            uint4* dst = (uint4*)WG;
            const uint4* sh = (const uint4*)gwhi;
            const uint4* sl = (const uint4*)gwlo;
            #pragma unroll
            for (int k = 0; k < 10; ++k) {
                int u = t + k * 256;
                int chunk = u >> 6, v = u & 63;
                int ks = chunk >> 2, ntp = chunk & 3;
                int src = (ks * 8 + half * 4 + ntp) * 64 + v;
                dst[u]        = sh[src];
                dst[2560 + u] = sl[src];
            }
        }

        int wave = t >> 6, lane = t & 63;
        int q = lane >> 4, r = lane & 15;
        const float* fp = featT + (size_t)(m0 + wave * 16 + r) * CC + q * 8;

        float fa[2][8];
        auto LOADA = [&](int ks, int buf) {
            const float4* p = (const float4*)(fp + ks * 32);
            *(float4*)&fa[buf][0] = p[0];
            *(float4*)&fa[buf][4] = p[1];
        };

        v4f acc[4];
        #pragma unroll
        for (int nt = 0; nt < 4; ++nt) acc[nt] = (v4f)0.f;

        LOADA(0, 0);
        __syncthreads();

        const bfrag* WGH = (const bfrag*)WG;
        const bfrag* WGL = (const bfrag*)(WG + 20480);

        #pragma unroll
        for (int ks = 0; ks < 10; ++ks) {
            int cur = ks & 1;
            if (ks < 9) LOADA(ks + 1, cur ^ 1);
            bfrag ah, al;
            #pragma unroll
            for (int kk = 0; kk < 8; ++kk) {
                float d = fa[cur][kk];
                __bf16 h = (__bf16)d;
                ah[kk] = h;
                al[kk] = (__bf16)(d - (float)h);
            }
            #pragma unroll
            for (int nt = 0; nt < 4; ++nt) {
                bfrag bh = WGH[((ks * 4 + nt) << 6) + lane];
                bfrag bl = WGL[((ks * 4 + nt) << 6) + lane];
                acc[nt] = __builtin_amdgcn_mfma_f32_16x16x32_bf16(ah, bh, acc[nt], 0, 0, 0);
                acc[nt] = __builtin_amdgcn_mfma_f32_16x16x32_bf16(ah, bl, acc[nt], 0, 0, 0);
                acc[nt] = __builtin_amdgcn_mfma_f32_16x16x32_bf16(al, bh, acc[nt], 0, 0, 0);
            }
        }
        #pragma unroll
        for (int nt = 0; nt < 4; ++nt) {
            #pragma unroll
            for (int reg = 0; reg < 4; ++reg) {
                int m = m0 + wave * 16 + q * 4 + reg;
                g1[(size_t)m * GH + (half * 4 + nt) * 16 + r] =
                    __float2half(acc[nt][reg]);
            }
        }
    } else {
        // ---------- edge_val branch: undirected edges, dual scatter --------
        float* ca = (float*)WG;
        float* cb = ca + PH;
        int* kpl = (int*)(cb + PH);
        int blk = blockIdx.x - nGC;
        int b = blk % BB;
        int u = (blk / BB) * 256 + t;
        if (t < PH) {
            int l = t;
            float mu = Ssum[b * PH + l] / E;
            float var = S2sum[b * PH + l] / E - mu * mu;
            float A = rsqrtf(var + 1e-5f) * gamma[l];
            ca[l] = A;
            cb[l] = beta[l] - mu * A;
        }
        if (t < 48) kpl[t] = pairs[((size_t)b * E + t * 47) * 2];
        __syncthreads();
        if (u >= NUD) return;

        int i, j, hrow;
        if (u < NKPH) {
            int a, yk;
            tri_decode(u, a, yk);
            i = kpl[a]; j = kpl[yk];
            hrow = a * 47 + yk - 1;
        } else {
            int up = u - NKPH;           // [0, 3906) forward-region offset
            int pf, ww, y0, x0, dy, dx;
            if (up < 961)       { pf = 0;    ww = 31; y0 = 1; x0 = 1; dy = -1; dx = -1; }
            else if (up < 1953) { pf = 961;  ww = 32; y0 = 1; x0 = 0; dy = -1; dx = 0;  }
            else if (up < 2914) { pf = 1953; ww = 31; y0 = 1; x0 = 0; dy = -1; dx = 1;  }
            else                { pf = 2914; ww = 31; y0 = 0; x0 = 1; dy = 0;  dx = -1; }
            int rel = up - pf;
            int yR = rel / ww, xC = rel - yR * ww;
            int yy = yR + y0, xi = xC + x0;
            i = yy * 32 + xi;
            j = (yy + dy) * 32 + (xi + dx);
            hrow = EKP + up;             // undirected ng id == forward hstore offset
        }

        const bfrag* hp = (const bfrag*)(hstore + ((size_t)b * E + hrow) * PH);
        float acc = 0.f;
        #pragma unroll
        for (int l8 = 0; l8 < 8; ++l8) {
            bfrag hv = hp[l8];
            #pragma unroll
            for (int c = 0; c < 8; ++c) {
                int l = l8 * 8 + c;
                float x = fmaf((float)hv[c], ca[l], cb[l]);
                x = x > 0.f ? x : 0.f;
                acc = fmaf(x, w2[l], acc);
            }
        }
        float edge = 1.f / (1.f + __expf(-(acc + b2[0])));
        int ri = b * NN + i;
        int rj = b * NN + j;
        int s1 = atomicAdd(&cnt[ri], 1);
        if (s1 < ELLW) {
            ecol[ri * ELLW + s1]  = j;
            eval_[ri * ELLW + s1] = edge;
        }
        int s2 = atomicAdd(&cnt[rj], 1);
        if (s2 < ELLW) {
            ecol[rj * ELLW + s2]  = i;
            eval_[rj * ELLW + s2] = edge;
        }
    }
}

// ------- stage 5: g2 = (leaky(adj@g1)) @ gc2_w  (4 nodes/block, f16 g1) --
__global__ __launch_bounds__(256) void k_spmm1(
    const __half* __restrict__ g1, const int* __restrict__ cnt,
    const int* __restrict__ ecol, const float* __restrict__ eval_,
    const float* __restrict__ w2g, float* __restrict__ g2)
{
    int tid = threadIdx.x & 63;
    int node = blockIdx.x * 4 + (threadIdx.x >> 6);
    int base = node & ~(NN - 1);
    float wa = w2g[2 * tid], wb = w2g[2 * tid + 1];
    int c = cnt[node];
    const int* ec = ecol + (size_t)node * ELLW;
    const float* ev = eval_ + (size_t)node * ELLW;
    const __half2* g1v = (const __half2*)g1;
    float aa = 0.f, ab = 0.f;
    int s = 0;
    for (; s + 4 <= c; s += 4) {
        int j0 = ec[s], j1 = ec[s + 1], j2 = ec[s + 2], j3 = ec[s + 3];
        float v0 = ev[s], v1 = ev[s + 1], v2 = ev[s + 2], v3 = ev[s + 3];
        __half2 u0 = g1v[((size_t)(base + j0)) * 64 + tid];
        __half2 u1 = g1v[((size_t)(base + j1)) * 64 + tid];
        __half2 u2 = g1v[((size_t)(base + j2)) * 64 + tid];
        __half2 u3 = g1v[((size_t)(base + j3)) * 64 + tid];
        aa = fmaf(v0, __low2float(u0), aa); ab = fmaf(v0, __high2float(u0), ab);
        aa = fmaf(v1, __low2float(u1), aa); ab = fmaf(v1, __high2float(u1), ab);
        aa = fmaf(v2, __low2float(u2), aa); ab = fmaf(v2, __high2float(u2), ab);
        aa = fmaf(v3, __low2float(u3), aa); ab = fmaf(v3, __high2float(u3), ab);
    }
    for (; s < c; ++s) {
        __half2 u = g1v[((size_t)(base + ec[s])) * 64 + tid];
        float v = ev[s];
        aa = fmaf(v, __low2float(u), aa); ab = fmaf(v, __high2float(u), ab);
    }
    float h1a = aa > 0.f ? aa : 0.2f * aa;
    float h1b = ab > 0.f ? ab : 0.2f * ab;
    float p = h1a * wa + h1b * wb;
    #pragma unroll
    for (int off = 32; off >= 1; off >>= 1) p += __shfl_down(p, off, 64);
    if (tid == 0) g2[node] = p;
}

// ------------- stage 6: out = sigmoid(adj @ g2) (4 nodes/block) ----------
__global__ __launch_bounds__(256) void k_spmm2(
    const float* __restrict__ g2, const int* __restrict__ cnt,
    const int* __restrict__ ecol, const float* __restrict__ eval_,
    float* __restrict__ out)
{
    int lane = threadIdx.x & 63;
    int node = blockIdx.x * 4 + (threadIdx.x >> 6);
    int base = node & ~(NN - 1);
    int c = cnt[node];
    float p = 0.f;
    if (lane < c) {
        int j = ecol[(size_t)node * ELLW + lane];
        p = eval_[(size_t)node * ELLW + lane] * g2[base + j];
    }
    #pragma unroll
    for (int off = 32; off >= 1; off >>= 1) p += __shfl_down(p, off, 64);
    if (lane == 0) out[node] = 1.f / (1.f + __expf(-p));
}

extern "C" void kernel_launch(void* const* d_in, const int* in_sizes, int n_in,
                              void* d_out, int out_size, void* d_ws, size_t ws_size,
                              hipStream_t stream)
{
    const float* search = (const float*)d_in[0];
    const float* xcorr  = (const float*)d_in[1];
    const int*   pairs  = (const int*)d_in[2];
    const float* w1     = (const float*)d_in[3];
    const float* b1     = (const float*)d_in[4];
    const float* gamma  = (const float*)d_in[5];
    const float* beta   = (const float*)d_in[6];
    const float* w2     = (const float*)d_in[7];
    const float* b2     = (const float*)d_in[8];
    const float* gc1w   = (const float*)d_in[9];
    const float* gc2w   = (const float*)d_in[10];
    float* out = (float*)d_out;

    int E   = in_sizes[2] / (BB * 2);    // 10068
    int EKP = E - NENG;                  // 2256 keypoint-clique edges
    int nbU  = (NUD + 255) / 256;        // 20 undirected-edge tiles
    int nGC  = BB * 32;                  // 512 gc1 blocks

    char* ws = (char*)d_ws;
    size_t off = 0;
    auto alloc = [&](size_t bytes) {
        size_t o = off;
        off += (bytes + 255) & ~(size_t)255;
        return o;
    };
    __bf16* whi   = (__bf16*)(ws + alloc(10 * 4 * 64 * 8 * 2));   // 40960 B
    __bf16* wlo   = (__bf16*)(ws + alloc(10 * 4 * 64 * 8 * 2));   // contiguous after whi
    __bf16* gwhi  = (__bf16*)(ws + alloc(10 * 8 * 64 * 8 * 2));
    __bf16* gwlo  = (__bf16*)(ws + alloc(10 * 8 * 64 * 8 * 2));
    float* featT  = (float*)(ws + alloc((size_t)BB * NN * CC * 4));
    bf16*  hstore = (bf16*)(ws + alloc((size_t)BB * E * PH * 2));
    float* Ssum   = (float*)(ws + alloc(BB * PH * 4));
    float* S2sum  = (float*)(ws + alloc(BB * PH * 4));
    int*   cnt    = (int*)(ws + alloc(BB * NN * 4));
    int*   ecol   = (int*)(ws + alloc((size_t)BB * NN * ELLW * 4));
    float* eval_  = (float*)(ws + alloc((size_t)BB * NN * ELLW * 4));
    __half* g1    = (__half*)(ws + alloc((size_t)BB * NN * GH * 2));
    float* g2     = (float*)(ws + alloc(BB * NN * 4));
    (void)ws_size; (void)n_in; (void)out_size;

    k_prep_transpose<<<dim3(BB * 320 + 160), dim3(256), 0, stream>>>(
        search, xcorr, featT, w1, gc1w, whi, wlo, gwhi, gwlo, cnt, Ssum, S2sum);
    k_edge<<<dim3(BB * 16), dim3(512), 0, stream>>>(featT, pairs,
                                                    (const uint4*)whi, b1,
                                                    hstore, Ssum, S2sum,
                                                    E, EKP);
    k_val_gc1<<<dim3(nGC + BB * nbU), dim3(256), 0, stream>>>(
        featT, gwhi, gwlo, g1, hstore, Ssum, S2sum, gamma, beta, w2, b2,
        pairs, cnt, ecol, eval_, E, EKP, nGC);
    k_spmm1<<<dim3(BB * NN / 4), dim3(256), 0, stream>>>(g1, cnt, ecol, eval_,
                                                         gc2w, g2);
    k_spmm2<<<dim3(BB * NN / 4), dim3(256), 0, stream>>>(g2, cnt, ecol, eval_, out);
}